// Round 6
// baseline (279.979 us; speedup 1.0000x reference)
//
#include <hip/hip_runtime.h>
#include <hip/hip_bf16.h>
#include <math.h>

#define Bb 2
#define Ss 2048
#define Dd 1024
#define Hh 16
#define DKk 64
#define BSn (Bb*Ss)

typedef unsigned short u16;
typedef __attribute__((ext_vector_type(8))) short frag_ab;   // 8 bf16
typedef __attribute__((ext_vector_type(4))) float frag_cd;   // 4 f32

static __device__ __forceinline__ u16 f2bf(float x) {
    __hip_bfloat16 h = __float2bfloat16(x);
    return *reinterpret_cast<u16*>(&h);
}

// Direct global->LDS async copy, 16B per lane. LDS dest is the wave-uniform
// base; HW writes lane i at base + i*16B. Requires LINEAR (unpadded) LDS.
static __device__ __forceinline__ void gload16(const u16* g, u16* l) {
    __builtin_amdgcn_global_load_lds(
        (const __attribute__((address_space(1))) void*)g,
        (__attribute__((address_space(3))) void*)l, 16, 0, 0);
}

// ---------------------------------------------------------------------------
// One-shot convert: q,k,v fp32 -> bf16; W* fp32 [k][n] -> bf16 transposed [n][k].
// ---------------------------------------------------------------------------
__global__ __launch_bounds__(256)
void convert_kernel(const float* __restrict__ q, const float* __restrict__ k,
                    const float* __restrict__ v,
                    const float* __restrict__ Wq, const float* __restrict__ Wk,
                    const float* __restrict__ Wv, const float* __restrict__ Wo,
                    u16* __restrict__ qb, u16* __restrict__ kb, u16* __restrict__ vb,
                    u16* __restrict__ wqt, u16* __restrict__ wkt,
                    u16* __restrict__ wvt, u16* __restrict__ wot)
{
    __shared__ u16 T[64 * 80];
    const int tid = threadIdx.x;
    const int bid = blockIdx.x;
    if (bid < 3072) {
        int t = bid >> 10;
        const float* src = (t == 0) ? q : (t == 1) ? k : v;
        u16* dst = (t == 0) ? qb : (t == 1) ? kb : vb;
        size_t base = (size_t)(bid & 1023) * 4096;
#pragma unroll
        for (int i = 0; i < 4; ++i) {
            size_t e = base + (size_t)(tid + i * 256) * 4;
            float4 xv = *(const float4*)(src + e);
            ushort4 o;
            o.x = f2bf(xv.x); o.y = f2bf(xv.y); o.z = f2bf(xv.z); o.w = f2bf(xv.w);
            *(ushort4*)(dst + e) = o;
        }
    } else {
        int wbid = bid - 3072;
        int w = wbid >> 8;
        const float* src = (w == 0) ? Wq : (w == 1) ? Wk : (w == 2) ? Wv : Wo;
        u16* dst = (w == 0) ? wqt : (w == 1) ? wkt : (w == 2) ? wvt : wot;
        int t = wbid & 255;
        int k0 = (t >> 4) * 64, nt0 = (t & 15) * 64;
#pragma unroll
        for (int i = 0; i < 4; ++i) {
            int f = tid + i * 256;
            int kk = f >> 4, nn = (f & 15) * 4;
            float4 xv = *(const float4*)(src + (size_t)(k0 + kk) * Dd + nt0 + nn);
            T[(nn + 0) * 80 + kk] = f2bf(xv.x);
            T[(nn + 1) * 80 + kk] = f2bf(xv.y);
            T[(nn + 2) * 80 + kk] = f2bf(xv.z);
            T[(nn + 3) * 80 + kk] = f2bf(xv.w);
        }
        __syncthreads();
#pragma unroll
        for (int i = 0; i < 2; ++i) {
            int g = tid + i * 256;
            int nn = g >> 3, k8 = (g & 7) * 8;
            *(uint4*)(dst + (size_t)(nt0 + nn) * Dd + k0 + k8) =
                *(const uint4*)&T[nn * 80 + k8];
        }
    }
}

// ---------------------------------------------------------------------------
// bf16 MFMA GEMM — R4 version (WIN), unchanged except mode-1 (Q) scale now
// folds log2(e) so attention softmax can run in exp2 domain:
//   sc = 1/sqrt(64) * log2(e) = 0.125 * 1.4426950408889634
// R1 post-mortem (refined by R4): write-amplification came from TILE GROWTH
// register pressure, not gload_lds. Do not grow acc/fragment count.
// ---------------------------------------------------------------------------
__global__ __launch_bounds__(256)
void gemm_bf16(const u16* __restrict__ X0, const u16* __restrict__ X1,
               const u16* __restrict__ X2,
               const u16* __restrict__ W0, const u16* __restrict__ W1,
               const u16* __restrict__ W2,
               const float* __restrict__ b0, const float* __restrict__ b1,
               const float* __restrict__ b2,
               u16* __restrict__ O0, u16* __restrict__ O1, u16* __restrict__ O2,
               float* __restrict__ OutF, int fused)
{
    __shared__ u16 As[128 * 64];
    __shared__ u16 Bs[64 * 64];

    const int tid = threadIdx.x;
    const int wv = tid >> 6, lane = tid & 63, l16 = lane & 15, quad = lane >> 4;
    const int n0 = blockIdx.x * 64, m0 = blockIdx.y * 128;
    const int z = blockIdx.z;

    const u16* X      = fused ? ((z == 0) ? X0 : (z == 1) ? X1 : X2) : X0;
    const u16* Wt     = fused ? ((z == 0) ? W0 : (z == 1) ? W1 : W2) : W0;
    const float* bias = fused ? ((z == 0) ? b0 : (z == 1) ? b1 : b2) : b0;
    u16* OutB         = (z == 0) ? O0 : (z == 1) ? O1 : O2;
    const int mode    = fused ? ((z == 0) ? 1 : (z == 1) ? 3 : 2) : 0;

    const int srow = tid >> 3;            // p-chunk row 0..31
    const int scol = (tid & 7) * 8;

    frag_cd acc[2][4];
#pragma unroll
    for (int ms = 0; ms < 2; ++ms)
#pragma unroll
        for (int n = 0; n < 4; ++n) acc[ms][n] = (frag_cd){0.f, 0.f, 0.f, 0.f};

    for (int k0 = 0; k0 < Dd; k0 += 64) {
        __syncthreads();   // prev-iter LDS readers done
#pragma unroll
        for (int p = 0; p < 4; ++p)
            gload16(&X[(size_t)(m0 + p * 32 + srow) * Dd + k0 + scol],
                    &As[p * 2048 + wv * 512]);
#pragma unroll
        for (int p = 0; p < 2; ++p)
            gload16(&Wt[(size_t)(n0 + p * 32 + srow) * Dd + k0 + scol],
                    &Bs[p * 2048 + wv * 512]);
        __syncthreads();   // compiler drains vmcnt(0) here: staging complete

#pragma unroll
        for (int ks = 0; ks < 2; ++ks) {
            frag_ab a0 = *(const frag_ab*)&As[(wv * 32 + l16) * 64 + ks * 32 + quad * 8];
            frag_ab a1 = *(const frag_ab*)&As[(wv * 32 + 16 + l16) * 64 + ks * 32 + quad * 8];
#pragma unroll
            for (int n = 0; n < 4; ++n) {
                frag_ab b = *(const frag_ab*)&Bs[(n * 16 + l16) * 64 + ks * 32 + quad * 8];
                acc[0][n] = __builtin_amdgcn_mfma_f32_16x16x32_bf16(a0, b, acc[0][n], 0, 0, 0);
                acc[1][n] = __builtin_amdgcn_mfma_f32_16x16x32_bf16(a1, b, acc[1][n], 0, 0, 0);
            }
        }
    }

    float bv4[4];
#pragma unroll
    for (int n = 0; n < 4; ++n) bv4[n] = bias[n0 + n * 16 + l16];

    if (mode == 0) {
#pragma unroll
        for (int ms = 0; ms < 2; ++ms)
#pragma unroll
            for (int r = 0; r < 4; ++r) {
                int row = m0 + wv * 32 + ms * 16 + quad * 4 + r;
#pragma unroll
                for (int n = 0; n < 4; ++n)
                    OutF[(size_t)row * Dd + n0 + n * 16 + l16] = acc[ms][n][r] + bv4[n];
            }
    } else if (mode == 2) {
        const int h = n0 >> 6;
        const int b = m0 >> 11;
#pragma unroll
        for (int ms = 0; ms < 2; ++ms) {
            int sbase = (m0 & (Ss - 1)) + wv * 32 + ms * 16 + quad * 4;
#pragma unroll
            for (int n = 0; n < 4; ++n) {
                int d = n * 16 + l16;
                ushort4 o;
                o.x = f2bf(acc[ms][n][0] + bv4[n]);
                o.y = f2bf(acc[ms][n][1] + bv4[n]);
                o.z = f2bf(acc[ms][n][2] + bv4[n]);
                o.w = f2bf(acc[ms][n][3] + bv4[n]);
                *(ushort4*)&OutB[(((size_t)b * Hh + h) * DKk + d) * Ss + sbase] = o;
            }
        }
    } else {
        const int h = n0 >> 6;
        const float lg = 0.28782313662425575f;  // ln(10000)/32
        // mode 1 (Q): fold 1/sqrt(DK) AND log2(e) for exp2-domain softmax
        const float sc = (mode == 1) ? 0.18033688011112042f : 1.0f;
#pragma unroll
        for (int ms = 0; ms < 2; ++ms)
#pragma unroll
            for (int r = 0; r < 4; ++r) {
                int row = m0 + wv * 32 + ms * 16 + quad * 4 + r;
                int b = row >> 11, s = row & (Ss - 1);
                u16* orow = OutB + (((size_t)b * Hh + h) * Ss + s) * DKk;
#pragma unroll
                for (int n = 0; n < 2; ++n) {
                    int j = n * 16 + l16;
                    float ang = (float)s * __expf(-(float)j * lg);
                    float cv = cosf(ang), sv = sinf(ang);
                    float lo = acc[ms][n][r] + bv4[n];
                    float hi = acc[ms][n + 2][r] + bv4[n + 2];
                    orow[j]      = f2bf((lo * cv - hi * sv) * sc);
                    orow[j + 32] = f2bf((hi * cv + lo * sv) * sc);
                }
            }
    }
}

// ---------------------------------------------------------------------------
// MFMA flash attention — R5 body with three changes:
//  1. Qs also via gload16+swizzle (proven K-path), Ps -> swizzled [64][64]:
//     LDS 34816 -> 32768 exactly => 5 blocks/CU (was 4), 20 waves/CU peak.
//     Ps involution: store P(row,col) at col^((row&7)<<3); b128 read at
//     g^((row&7)<<3) retrieves P(row,g..g+7) since ((g^x)+j)^x = g+j for
//     8-aligned g, j<8, x in bits 3..5.
//  2. exp2-domain softmax (Q pre-scaled by log2e in gemm): exp2f = native
//     v_exp_f32, one less mul per exp.
//  3. T13 defer-max: skip {alpha, of-rescale, l_r mul} when wave-wide max
//     growth <= 8 (log2 units => P <= 256; bf16/f32 safe). Wave-uniform
//     branch, no barriers inside. First iter always takes the full path.
// TRIPWIRES: absmax <= 0.0078125; conflicts ~1.1M; WRITE_SIZE 8MB.
// ---------------------------------------------------------------------------
__global__ __launch_bounds__(256)
void attn_mfma(const u16* __restrict__ Q, const u16* __restrict__ K,
               const u16* __restrict__ Vt, u16* __restrict__ Aout)
{
    __shared__ u16 Qs[64 * 64];
    __shared__ u16 Ks[64 * 64];
    __shared__ u16 Vs[64 * 64];
    __shared__ u16 Ps[64 * 64];

    const int tid = threadIdx.x;
    const int wv = tid >> 6;
    const int lane = tid & 63;
    const int l16 = lane & 15;
    const int quad = lane >> 4;

    const int bh = blockIdx.y;
    // balanced work swizzle: a CU's resident blocks get qb chains whose
    // lengths sum near-constant (see R3 header derivation)
    const int vsw = (blockIdx.x + (bh & 7)) & 31;
    const int jj  = bh >> 3;
    const int qb  = (jj == 0) ? vsw
                  : (jj == 1) ? ((vsw + 8) & 31)
                  : (jj == 2) ? ((23 - vsw) & 31)
                  :             (31 - vsw);
    const int q0 = qb * 64;

    const size_t qkbase = (size_t)bh * Ss * DKk;
    const size_t vbase  = (size_t)bh * DKk * Ss;
    const int b = bh >> 4, h = bh & 15;

    // staging geometry (gload_lds): lane -> (row = tid>>3 within 32-row chunk,
    // slot = tid&7). Source col pre-swizzled by row&7 (rule 21).
    const int srow = tid >> 3;                       // 0..31
    const int scol = ((tid & 7) ^ (srow & 7)) * 8;   // swizzled global col (u16)
    const int sx   = (l16 & 7) * 8;                  // read-side XOR (u16)

    // stage the Q tile once via gload16 (drained by kb=0's vmcnt(0) barrier)
#pragma unroll
    for (int p = 0; p < 2; ++p)
        gload16(&Q[qkbase + (size_t)(q0 + p * 32 + srow) * DKk + scol],
                &Qs[p * 2048 + wv * 512]);

    float m_r[4], l_r[4];
#pragma unroll
    for (int r = 0; r < 4; ++r) { m_r[r] = -3.0e38f; l_r[r] = 0.f; }
    frag_cd of[4];
#pragma unroll
    for (int n = 0; n < 4; ++n) of[n] = (frag_cd){0.f, 0.f, 0.f, 0.f};

    for (int kb = 0; kb <= qb; ++kb) {
        const int k0 = kb * 64;
        __syncthreads();   // prev-iter Ks/Vs/Ps readers done
#pragma unroll
        for (int p = 0; p < 2; ++p) {
            gload16(&K[qkbase + (size_t)(k0 + p * 32 + srow) * DKk + scol],
                    &Ks[p * 2048 + wv * 512]);
            gload16(&Vt[vbase + (size_t)(p * 32 + srow) * Ss + k0 + scol],
                    &Vs[p * 2048 + wv * 512]);
        }
        __syncthreads();   // drains vmcnt(0): staging complete

        frag_cd sf[4];
#pragma unroll
        for (int n = 0; n < 4; ++n) sf[n] = (frag_cd){0.f, 0.f, 0.f, 0.f};
#pragma unroll
        for (int h2 = 0; h2 < 2; ++h2) {
            frag_ab qa = *(const frag_ab*)&Qs[(wv * 16 + l16) * 64 + ((h2 * 32 + quad * 8) ^ sx)];
#pragma unroll
            for (int n = 0; n < 4; ++n) {
                frag_ab kf = *(const frag_ab*)&Ks[(n * 16 + l16) * 64 + ((h2 * 32 + quad * 8) ^ sx)];
                sf[n] = __builtin_amdgcn_mfma_f32_16x16x32_bf16(qa, kf, sf[n], 0, 0, 0);
            }
        }

        if (kb == qb) {
#pragma unroll
            for (int r = 0; r < 4; ++r) {
                int qi = wv * 16 + quad * 4 + r;
#pragma unroll
                for (int n = 0; n < 4; ++n)
                    if (n * 16 + l16 > qi) sf[n][r] = -1.0e30f;
            }
        }

        // --- online softmax, exp2 domain, defer-max ---
        float mx4[4];
        bool need = false;
#pragma unroll
        for (int r = 0; r < 4; ++r) {
            float mx = m_r[r];
#pragma unroll
            for (int n = 0; n < 4; ++n) mx = fmaxf(mx, sf[n][r]);
#pragma unroll
            for (int off = 1; off < 16; off <<= 1) mx = fmaxf(mx, __shfl_xor(mx, off));
            mx4[r] = mx;
            need = need || (mx > m_r[r] + 8.0f);
        }
        if (__any(need)) {   // wave-uniform: rescale path
#pragma unroll
            for (int r = 0; r < 4; ++r) {
                float a = exp2f(m_r[r] - mx4[r]);
                m_r[r] = mx4[r];
                l_r[r] *= a;
#pragma unroll
                for (int n = 0; n < 4; ++n) of[n][r] *= a;
            }
        }
#pragma unroll
        for (int r = 0; r < 4; ++r) {
            float sum = 0.f;
#pragma unroll
            for (int n = 0; n < 4; ++n) {
                float p = exp2f(sf[n][r] - m_r[r]);   // <= 2^8 when deferred
                sf[n][r] = p;
                sum += p;
            }
#pragma unroll
            for (int off = 1; off < 16; off <<= 1) sum += __shfl_xor(sum, off);
            l_r[r] += sum;
        }

        // P -> LDS, swizzled (write col ^ ((row&7)<<3); read undoes it)
#pragma unroll
        for (int n = 0; n < 4; ++n)
#pragma unroll
            for (int r = 0; r < 4; ++r) {
                int row = wv * 16 + quad * 4 + r;
                Ps[row * 64 + ((n * 16 + l16) ^ ((row & 7) << 3))] = f2bf(sf[n][r]);
            }
        __threadfence_block();   // wave-private P strip: intra-wave order only

#pragma unroll
        for (int h2 = 0; h2 < 2; ++h2) {
            frag_ab pa = *(const frag_ab*)&Ps[(wv * 16 + l16) * 64 + ((h2 * 32 + quad * 8) ^ sx)];
#pragma unroll
            for (int n = 0; n < 4; ++n) {
                frag_ab vf = *(const frag_ab*)&Vs[(n * 16 + l16) * 64 + ((h2 * 32 + quad * 8) ^ sx)];
                of[n] = __builtin_amdgcn_mfma_f32_16x16x32_bf16(pa, vf, of[n], 0, 0, 0);
            }
        }
    }

#pragma unroll
    for (int r = 0; r < 4; ++r) {
        float inv = 1.f / l_r[r];
        int row = q0 + wv * 16 + quad * 4 + r;
        u16* orow = Aout + ((size_t)b * Ss + row) * Dd + h * DKk;
#pragma unroll
        for (int n = 0; n < 4; ++n) orow[n * 16 + l16] = f2bf(of[n][r] * inv);
    }
}

extern "C" void kernel_launch(void* const* d_in, const int* in_sizes, int n_in,
                              void* d_out, int out_size, void* d_ws, size_t ws_size,
                              hipStream_t stream) {
    (void)in_sizes; (void)n_in; (void)out_size;
    const float* q  = (const float*)d_in[0];
    const float* k  = (const float*)d_in[1];
    const float* v  = (const float*)d_in[2];
    // d_in[3] = mask (tril causal) -- enforced analytically in attn_mfma
    const float* Wq = (const float*)d_in[4];
    const float* bq = (const float*)d_in[5];
    const float* Wk = (const float*)d_in[6];
    const float* bk = (const float*)d_in[7];
    const float* Wv = (const float*)d_in[8];
    const float* bv = (const float*)d_in[9];
    const float* Wo = (const float*)d_in[10];
    const float* bo = (const float*)d_in[11];
    float* out = (float*)d_out;

    const size_t E = (size_t)Bb * Ss * Dd;     // 4,194,304
    const size_t Wn = (size_t)Dd * Dd;         // 1,048,576
    const size_t need = (7 * E + 4 * Wn) * sizeof(u16);   // 64 MiB
    if (ws_size < need) return;
    u16* qa  = (u16*)d_ws;
    u16* ka  = qa + E;
    u16* va  = ka + E;
    u16* wqt = va + E;
    u16* wkt = wqt + Wn;
    u16* wvt = wkt + Wn;
    u16* wot = wvt + Wn;
    u16* Qh  = wot + Wn;
    u16* Kh  = Qh + E;
    u16* Vth = Kh + E;
    u16* Abf = Vth + E;

    convert_kernel<<<4096, 256, 0, stream>>>(q, k, v, Wq, Wk, Wv, Wo,
                                             qa, ka, va, wqt, wkt, wvt, wot);
    gemm_bf16<<<dim3(Dd / 64, BSn / 128, 3), 256, 0, stream>>>(
        qa, ka, va, wqt, wkt, wvt, bq, bk, bv, Qh, Kh, Vth, nullptr, 1);
    attn_mfma<<<dim3(32, Bb * Hh), 256, 0, stream>>>(Qh, Kh, Vth, Abf);
    gemm_bf16<<<dim3(Dd / 64, BSn / 128, 1), 256, 0, stream>>>(
        Abf, nullptr, nullptr, wot, nullptr, nullptr, bo, nullptr, nullptr,
        nullptr, nullptr, nullptr, out, 0);
}

// Round 7
// 274.818 us; speedup vs baseline: 1.0188x; 1.0188x over previous
//
#include <hip/hip_runtime.h>
#include <hip/hip_bf16.h>
#include <math.h>

#define Bb 2
#define Ss 2048
#define Dd 1024
#define Hh 16
#define DKk 64
#define BSn (Bb*Ss)

typedef unsigned short u16;
typedef __attribute__((ext_vector_type(8))) short frag_ab;   // 8 bf16
typedef __attribute__((ext_vector_type(4))) float frag_cd;   // 4 f32

static __device__ __forceinline__ u16 f2bf(float x) {
    __hip_bfloat16 h = __float2bfloat16(x);
    return *reinterpret_cast<u16*>(&h);
}

// Direct global->LDS async copy, 16B per lane. LDS dest is the wave-uniform
// base; HW writes lane i at base + i*16B. Requires LINEAR (unpadded) LDS.
static __device__ __forceinline__ void gload16(const u16* g, u16* l) {
    __builtin_amdgcn_global_load_lds(
        (const __attribute__((address_space(1))) void*)g,
        (__attribute__((address_space(3))) void*)l, 16, 0, 0);
}

// ---------------------------------------------------------------------------
// One-shot convert: q,k,v fp32 -> bf16; W* fp32 [k][n] -> bf16 transposed [n][k].
// ---------------------------------------------------------------------------
__global__ __launch_bounds__(256)
void convert_kernel(const float* __restrict__ q, const float* __restrict__ k,
                    const float* __restrict__ v,
                    const float* __restrict__ Wq, const float* __restrict__ Wk,
                    const float* __restrict__ Wv, const float* __restrict__ Wo,
                    u16* __restrict__ qb, u16* __restrict__ kb, u16* __restrict__ vb,
                    u16* __restrict__ wqt, u16* __restrict__ wkt,
                    u16* __restrict__ wvt, u16* __restrict__ wot)
{
    __shared__ u16 T[64 * 80];
    const int tid = threadIdx.x;
    const int bid = blockIdx.x;
    if (bid < 3072) {
        int t = bid >> 10;
        const float* src = (t == 0) ? q : (t == 1) ? k : v;
        u16* dst = (t == 0) ? qb : (t == 1) ? kb : vb;
        size_t base = (size_t)(bid & 1023) * 4096;
#pragma unroll
        for (int i = 0; i < 4; ++i) {
            size_t e = base + (size_t)(tid + i * 256) * 4;
            float4 xv = *(const float4*)(src + e);
            ushort4 o;
            o.x = f2bf(xv.x); o.y = f2bf(xv.y); o.z = f2bf(xv.z); o.w = f2bf(xv.w);
            *(ushort4*)(dst + e) = o;
        }
    } else {
        int wbid = bid - 3072;
        int w = wbid >> 8;
        const float* src = (w == 0) ? Wq : (w == 1) ? Wk : (w == 2) ? Wv : Wo;
        u16* dst = (w == 0) ? wqt : (w == 1) ? wkt : (w == 2) ? wvt : wot;
        int t = wbid & 255;
        int k0 = (t >> 4) * 64, nt0 = (t & 15) * 64;
#pragma unroll
        for (int i = 0; i < 4; ++i) {
            int f = tid + i * 256;
            int kk = f >> 4, nn = (f & 15) * 4;
            float4 xv = *(const float4*)(src + (size_t)(k0 + kk) * Dd + nt0 + nn);
            T[(nn + 0) * 80 + kk] = f2bf(xv.x);
            T[(nn + 1) * 80 + kk] = f2bf(xv.y);
            T[(nn + 2) * 80 + kk] = f2bf(xv.z);
            T[(nn + 3) * 80 + kk] = f2bf(xv.w);
        }
        __syncthreads();
#pragma unroll
        for (int i = 0; i < 2; ++i) {
            int g = tid + i * 256;
            int nn = g >> 3, k8 = (g & 7) * 8;
            *(uint4*)(dst + (size_t)(nt0 + nn) * Dd + k0 + k8) =
                *(const uint4*)&T[nn * 80 + k8];
        }
    }
}

// ---------------------------------------------------------------------------
// bf16 MFMA GEMM — R4/R5 version VERBATIM (WIN). Used for QKV only now
// (grid 1536 = exactly 6 blocks/CU co-resident).
// R1 post-mortem (refined by R4): write-amplification came from TILE GROWTH
// register pressure, not gload_lds. Do not grow acc/fragment count.
// ---------------------------------------------------------------------------
__global__ __launch_bounds__(256)
void gemm_bf16(const u16* __restrict__ X0, const u16* __restrict__ X1,
               const u16* __restrict__ X2,
               const u16* __restrict__ W0, const u16* __restrict__ W1,
               const u16* __restrict__ W2,
               const float* __restrict__ b0, const float* __restrict__ b1,
               const float* __restrict__ b2,
               u16* __restrict__ O0, u16* __restrict__ O1, u16* __restrict__ O2,
               float* __restrict__ OutF, int fused)
{
    __shared__ u16 As[128 * 64];
    __shared__ u16 Bs[64 * 64];

    const int tid = threadIdx.x;
    const int wv = tid >> 6, lane = tid & 63, l16 = lane & 15, quad = lane >> 4;
    const int n0 = blockIdx.x * 64, m0 = blockIdx.y * 128;
    const int z = blockIdx.z;

    const u16* X      = fused ? ((z == 0) ? X0 : (z == 1) ? X1 : X2) : X0;
    const u16* Wt     = fused ? ((z == 0) ? W0 : (z == 1) ? W1 : W2) : W0;
    const float* bias = fused ? ((z == 0) ? b0 : (z == 1) ? b1 : b2) : b0;
    u16* OutB         = (z == 0) ? O0 : (z == 1) ? O1 : O2;
    const int mode    = fused ? ((z == 0) ? 1 : (z == 1) ? 3 : 2) : 0;

    const int srow = tid >> 3;            // p-chunk row 0..31
    const int scol = (tid & 7) * 8;

    frag_cd acc[2][4];
#pragma unroll
    for (int ms = 0; ms < 2; ++ms)
#pragma unroll
        for (int n = 0; n < 4; ++n) acc[ms][n] = (frag_cd){0.f, 0.f, 0.f, 0.f};

    for (int k0 = 0; k0 < Dd; k0 += 64) {
        __syncthreads();   // prev-iter LDS readers done
#pragma unroll
        for (int p = 0; p < 4; ++p)
            gload16(&X[(size_t)(m0 + p * 32 + srow) * Dd + k0 + scol],
                    &As[p * 2048 + wv * 512]);
#pragma unroll
        for (int p = 0; p < 2; ++p)
            gload16(&Wt[(size_t)(n0 + p * 32 + srow) * Dd + k0 + scol],
                    &Bs[p * 2048 + wv * 512]);
        __syncthreads();   // compiler drains vmcnt(0) here: staging complete

#pragma unroll
        for (int ks = 0; ks < 2; ++ks) {
            frag_ab a0 = *(const frag_ab*)&As[(wv * 32 + l16) * 64 + ks * 32 + quad * 8];
            frag_ab a1 = *(const frag_ab*)&As[(wv * 32 + 16 + l16) * 64 + ks * 32 + quad * 8];
#pragma unroll
            for (int n = 0; n < 4; ++n) {
                frag_ab b = *(const frag_ab*)&Bs[(n * 16 + l16) * 64 + ks * 32 + quad * 8];
                acc[0][n] = __builtin_amdgcn_mfma_f32_16x16x32_bf16(a0, b, acc[0][n], 0, 0, 0);
                acc[1][n] = __builtin_amdgcn_mfma_f32_16x16x32_bf16(a1, b, acc[1][n], 0, 0, 0);
            }
        }
    }

    float bv4[4];
#pragma unroll
    for (int n = 0; n < 4; ++n) bv4[n] = bias[n0 + n * 16 + l16];

    if (mode == 0) {
#pragma unroll
        for (int ms = 0; ms < 2; ++ms)
#pragma unroll
            for (int r = 0; r < 4; ++r) {
                int row = m0 + wv * 32 + ms * 16 + quad * 4 + r;
#pragma unroll
                for (int n = 0; n < 4; ++n)
                    OutF[(size_t)row * Dd + n0 + n * 16 + l16] = acc[ms][n][r] + bv4[n];
            }
    } else if (mode == 2) {
        const int h = n0 >> 6;
        const int b = m0 >> 11;
#pragma unroll
        for (int ms = 0; ms < 2; ++ms) {
            int sbase = (m0 & (Ss - 1)) + wv * 32 + ms * 16 + quad * 4;
#pragma unroll
            for (int n = 0; n < 4; ++n) {
                int d = n * 16 + l16;
                ushort4 o;
                o.x = f2bf(acc[ms][n][0] + bv4[n]);
                o.y = f2bf(acc[ms][n][1] + bv4[n]);
                o.z = f2bf(acc[ms][n][2] + bv4[n]);
                o.w = f2bf(acc[ms][n][3] + bv4[n]);
                *(ushort4*)&OutB[(((size_t)b * Hh + h) * DKk + d) * Ss + sbase] = o;
            }
        }
    } else {
        const int h = n0 >> 6;
        const float lg = 0.28782313662425575f;  // ln(10000)/32
        const float sc = (mode == 1) ? 0.125f : 1.0f;
#pragma unroll
        for (int ms = 0; ms < 2; ++ms)
#pragma unroll
            for (int r = 0; r < 4; ++r) {
                int row = m0 + wv * 32 + ms * 16 + quad * 4 + r;
                int b = row >> 11, s = row & (Ss - 1);
                u16* orow = OutB + (((size_t)b * Hh + h) * Ss + s) * DKk;
#pragma unroll
                for (int n = 0; n < 2; ++n) {
                    int j = n * 16 + l16;
                    float ang = (float)s * __expf(-(float)j * lg);
                    float cv = cosf(ang), sv = sinf(ang);
                    float lo = acc[ms][n][r] + bv4[n];
                    float hi = acc[ms][n + 2][r] + bv4[n + 2];
                    orow[j]      = f2bf((lo * cv - hi * sv) * sc);
                    orow[j + 32] = f2bf((hi * cv + lo * sv) * sc);
                }
            }
    }
}

// ---------------------------------------------------------------------------
// Out-projection GEMM — NEW (R7): 64x64 tile for occupancy. The fused kernel
// at grid 512 was 2 blocks/CU (the same under-occupancy pattern R3 fixed in
// attn). 64x64: acc[4]=16 VGPR (SMALLER than proven footprint), LDS 16KB,
// grid (16,64)=1024 blocks = 4 blocks/CU. Same proven gload16 2-phase
// staging. Extra B-panel re-reads are L2-resident (Wt = 2MB total).
// ---------------------------------------------------------------------------
__global__ __launch_bounds__(256)
void gemm_out(const u16* __restrict__ X0, const u16* __restrict__ W0,
              const float* __restrict__ b0, float* __restrict__ OutF)
{
    __shared__ u16 As[64 * 64];
    __shared__ u16 Bs[64 * 64];

    const int tid = threadIdx.x;
    const int wv = tid >> 6, lane = tid & 63, l16 = lane & 15, quad = lane >> 4;
    const int n0 = blockIdx.x * 64, m0 = blockIdx.y * 64;

    const int srow = tid >> 3;            // p-chunk row 0..31
    const int scol = (tid & 7) * 8;

    frag_cd acc[4];
#pragma unroll
    for (int n = 0; n < 4; ++n) acc[n] = (frag_cd){0.f, 0.f, 0.f, 0.f};

    for (int k0 = 0; k0 < Dd; k0 += 64) {
        __syncthreads();   // prev-iter LDS readers done
#pragma unroll
        for (int p = 0; p < 2; ++p) {
            gload16(&X0[(size_t)(m0 + p * 32 + srow) * Dd + k0 + scol],
                    &As[p * 2048 + wv * 512]);
            gload16(&W0[(size_t)(n0 + p * 32 + srow) * Dd + k0 + scol],
                    &Bs[p * 2048 + wv * 512]);
        }
        __syncthreads();   // drains vmcnt(0): staging complete

#pragma unroll
        for (int ks = 0; ks < 2; ++ks) {
            frag_ab a0 = *(const frag_ab*)&As[(wv * 16 + l16) * 64 + ks * 32 + quad * 8];
#pragma unroll
            for (int n = 0; n < 4; ++n) {
                frag_ab b = *(const frag_ab*)&Bs[(n * 16 + l16) * 64 + ks * 32 + quad * 8];
                acc[n] = __builtin_amdgcn_mfma_f32_16x16x32_bf16(a0, b, acc[n], 0, 0, 0);
            }
        }
    }

    float bv4[4];
#pragma unroll
    for (int n = 0; n < 4; ++n) bv4[n] = b0[n0 + n * 16 + l16];

#pragma unroll
    for (int r = 0; r < 4; ++r) {
        int row = m0 + wv * 16 + quad * 4 + r;
#pragma unroll
        for (int n = 0; n < 4; ++n)
            OutF[(size_t)row * Dd + n0 + n * 16 + l16] = acc[n][r] + bv4[n];
    }
}

// ---------------------------------------------------------------------------
// MFMA flash attention — R5 version VERBATIM (measured 78.4us). R6's changes
// (LDS 32KB, Ps/Qs swizzle, exp2, defer-max) reverted wholesale: the LDS cut
// bought capacity 5/CU but the grid is EXACTLY 4/CU (1024 blocks/256 CU) so
// nothing was gained, and the micro-opts cost +7us of VALU/scheduling
// overhead. Conflicts 1.08M are NOT on the critical path here (R6 proved:
// conflicts->0 yet slower). Check grid vs capacity before buying occupancy.
// ---------------------------------------------------------------------------
__global__ __launch_bounds__(256)
void attn_mfma(const u16* __restrict__ Q, const u16* __restrict__ K,
               const u16* __restrict__ Vt, u16* __restrict__ Aout)
{
    __shared__ u16 Qs[64 * 72];
    __shared__ u16 Ks[64 * 64];
    __shared__ u16 Vs[64 * 64];
    __shared__ u16 Ps[64 * 72];

    const int tid = threadIdx.x;
    const int wv = tid >> 6;
    const int lane = tid & 63;
    const int l16 = lane & 15;
    const int quad = lane >> 4;

    const int bh = blockIdx.y;
    // balanced work swizzle: a CU's 4 resident blocks get qb summing to 66
    const int vsw = (blockIdx.x + (bh & 7)) & 31;
    const int jj  = bh >> 3;
    const int qb  = (jj == 0) ? vsw
                  : (jj == 1) ? ((vsw + 8) & 31)
                  : (jj == 2) ? ((23 - vsw) & 31)
                  :             (31 - vsw);
    const int q0 = qb * 64;

    const size_t qkbase = (size_t)bh * Ss * DKk;
    const size_t vbase  = (size_t)bh * DKk * Ss;
    const int b = bh >> 4, h = bh & 15;

    // staging geometry (gload_lds): lane -> (row = tid>>3 within 32-row chunk,
    // slot = tid&7). Source col pre-swizzled by row&7 (rule 21).
    const int srow = tid >> 3;                       // 0..31
    const int scol = ((tid & 7) ^ (srow & 7)) * 8;   // swizzled global col (u16)
    const int sx   = (l16 & 7) * 8;                  // read-side XOR (u16)

    // stage the Q tile once (padded, reg-staged; ordered by kb=0 barriers)
#pragma unroll
    for (int rep = 0; rep < 2; ++rep) {
        int g = tid + rep * 256;
        int row = g >> 3, c8 = (g & 7) * 8;
        *(uint4*)&Qs[row * 72 + c8] =
            *(const uint4*)&Q[qkbase + (size_t)(q0 + row) * DKk + c8];
    }

    float m_r[4], l_r[4];
#pragma unroll
    for (int r = 0; r < 4; ++r) { m_r[r] = -3.0e38f; l_r[r] = 0.f; }
    frag_cd of[4];
#pragma unroll
    for (int n = 0; n < 4; ++n) of[n] = (frag_cd){0.f, 0.f, 0.f, 0.f};

    for (int kb = 0; kb <= qb; ++kb) {
        const int k0 = kb * 64;
        __syncthreads();   // prev-iter Ks/Vs/Ps readers done
#pragma unroll
        for (int p = 0; p < 2; ++p) {
            gload16(&K[qkbase + (size_t)(k0 + p * 32 + srow) * DKk + scol],
                    &Ks[p * 2048 + wv * 512]);
            gload16(&Vt[vbase + (size_t)(p * 32 + srow) * Ss + k0 + scol],
                    &Vs[p * 2048 + wv * 512]);
        }
        __syncthreads();   // drains vmcnt(0): staging complete

        frag_cd sf[4];
#pragma unroll
        for (int n = 0; n < 4; ++n) sf[n] = (frag_cd){0.f, 0.f, 0.f, 0.f};
#pragma unroll
        for (int h2 = 0; h2 < 2; ++h2) {
            frag_ab qa = *(const frag_ab*)&Qs[(wv * 16 + l16) * 72 + h2 * 32 + quad * 8];
#pragma unroll
            for (int n = 0; n < 4; ++n) {
                frag_ab kf = *(const frag_ab*)&Ks[(n * 16 + l16) * 64 + ((h2 * 32 + quad * 8) ^ sx)];
                sf[n] = __builtin_amdgcn_mfma_f32_16x16x32_bf16(qa, kf, sf[n], 0, 0, 0);
            }
        }

        if (kb == qb) {
#pragma unroll
            for (int r = 0; r < 4; ++r) {
                int qi = wv * 16 + quad * 4 + r;
#pragma unroll
                for (int n = 0; n < 4; ++n)
                    if (n * 16 + l16 > qi) sf[n][r] = -1.0e30f;
            }
        }

        float alpha[4];
#pragma unroll
        for (int r = 0; r < 4; ++r) {
            float mx = m_r[r];
#pragma unroll
            for (int n = 0; n < 4; ++n) mx = fmaxf(mx, sf[n][r]);
#pragma unroll
            for (int off = 1; off < 16; off <<= 1) mx = fmaxf(mx, __shfl_xor(mx, off));
            float a = __expf(m_r[r] - mx);
            m_r[r] = mx;
            float sum = 0.f;
#pragma unroll
            for (int n = 0; n < 4; ++n) {
                float p = __expf(sf[n][r] - mx);
                sf[n][r] = p;
                sum += p;
            }
#pragma unroll
            for (int off = 1; off < 16; off <<= 1) sum += __shfl_xor(sum, off);
            l_r[r] = l_r[r] * a + sum;
            alpha[r] = a;
        }
#pragma unroll
        for (int n = 0; n < 4; ++n)
#pragma unroll
            for (int r = 0; r < 4; ++r) of[n][r] *= alpha[r];

#pragma unroll
        for (int n = 0; n < 4; ++n)
#pragma unroll
            for (int r = 0; r < 4; ++r)
                Ps[(wv * 16 + quad * 4 + r) * 72 + n * 16 + l16] = f2bf(sf[n][r]);
        __threadfence_block();   // wave-private P strip: intra-wave order only

#pragma unroll
        for (int h2 = 0; h2 < 2; ++h2) {
            frag_ab pa = *(const frag_ab*)&Ps[(wv * 16 + l16) * 72 + h2 * 32 + quad * 8];
#pragma unroll
            for (int n = 0; n < 4; ++n) {
                frag_ab vf = *(const frag_ab*)&Vs[(n * 16 + l16) * 64 + ((h2 * 32 + quad * 8) ^ sx)];
                of[n] = __builtin_amdgcn_mfma_f32_16x16x32_bf16(pa, vf, of[n], 0, 0, 0);
            }
        }
    }

#pragma unroll
    for (int r = 0; r < 4; ++r) {
        float inv = 1.f / l_r[r];
        int row = q0 + wv * 16 + quad * 4 + r;
        u16* orow = Aout + ((size_t)b * Ss + row) * Dd + h * DKk;
#pragma unroll
        for (int n = 0; n < 4; ++n) orow[n * 16 + l16] = f2bf(of[n][r] * inv);
    }
}

extern "C" void kernel_launch(void* const* d_in, const int* in_sizes, int n_in,
                              void* d_out, int out_size, void* d_ws, size_t ws_size,
                              hipStream_t stream) {
    (void)in_sizes; (void)n_in; (void)out_size;
    const float* q  = (const float*)d_in[0];
    const float* k  = (const float*)d_in[1];
    const float* v  = (const float*)d_in[2];
    // d_in[3] = mask (tril causal) -- enforced analytically in attn_mfma
    const float* Wq = (const float*)d_in[4];
    const float* bq = (const float*)d_in[5];
    const float* Wk = (const float*)d_in[6];
    const float* bk = (const float*)d_in[7];
    const float* Wv = (const float*)d_in[8];
    const float* bv = (const float*)d_in[9];
    const float* Wo = (const float*)d_in[10];
    const float* bo = (const float*)d_in[11];
    float* out = (float*)d_out;

    const size_t E = (size_t)Bb * Ss * Dd;     // 4,194,304
    const size_t Wn = (size_t)Dd * Dd;         // 1,048,576
    const size_t need = (7 * E + 4 * Wn) * sizeof(u16);   // 64 MiB
    if (ws_size < need) return;
    u16* qa  = (u16*)d_ws;
    u16* ka  = qa + E;
    u16* va  = ka + E;
    u16* wqt = va + E;
    u16* wkt = wqt + Wn;
    u16* wvt = wkt + Wn;
    u16* wot = wvt + Wn;
    u16* Qh  = wot + Wn;
    u16* Kh  = Qh + E;
    u16* Vth = Kh + E;
    u16* Abf = Vth + E;

    convert_kernel<<<4096, 256, 0, stream>>>(q, k, v, Wq, Wk, Wv, Wo,
                                             qa, ka, va, wqt, wkt, wvt, wot);
    gemm_bf16<<<dim3(Dd / 64, BSn / 128, 3), 256, 0, stream>>>(
        qa, ka, va, wqt, wkt, wvt, bq, bk, bv, Qh, Kh, Vth, nullptr, 1);
    attn_mfma<<<dim3(32, Bb * Hh), 256, 0, stream>>>(Qh, Kh, Vth, Abf);
    gemm_out<<<dim3(Dd / 64, BSn / 64), 256, 0, stream>>>(Abf, wot, bo, out);
}

// Round 8
// 274.389 us; speedup vs baseline: 1.0204x; 1.0016x over previous
//
#include <hip/hip_runtime.h>
#include <hip/hip_bf16.h>
#include <math.h>

#define Bb 2
#define Ss 2048
#define Dd 1024
#define Hh 16
#define DKk 64
#define BSn (Bb*Ss)

typedef unsigned short u16;
typedef __attribute__((ext_vector_type(8))) short frag_ab;   // 8 bf16
typedef __attribute__((ext_vector_type(4))) float frag_cd;   // 4 f32

static __device__ __forceinline__ u16 f2bf(float x) {
    __hip_bfloat16 h = __float2bfloat16(x);
    return *reinterpret_cast<u16*>(&h);
}

// Direct global->LDS async copy, 16B per lane. LDS dest is the wave-uniform
// base; HW writes lane i at base + i*16B. Requires LINEAR (unpadded) LDS.
static __device__ __forceinline__ void gload16(const u16* g, u16* l) {
    __builtin_amdgcn_global_load_lds(
        (const __attribute__((address_space(1))) void*)g,
        (__attribute__((address_space(3))) void*)l, 16, 0, 0);
}

// ---------------------------------------------------------------------------
// One-shot convert: q,k,v fp32 -> bf16; W* fp32 [k][n] -> bf16 transposed [n][k].
// ---------------------------------------------------------------------------
__global__ __launch_bounds__(256)
void convert_kernel(const float* __restrict__ q, const float* __restrict__ k,
                    const float* __restrict__ v,
                    const float* __restrict__ Wq, const float* __restrict__ Wk,
                    const float* __restrict__ Wv, const float* __restrict__ Wo,
                    u16* __restrict__ qb, u16* __restrict__ kb, u16* __restrict__ vb,
                    u16* __restrict__ wqt, u16* __restrict__ wkt,
                    u16* __restrict__ wvt, u16* __restrict__ wot)
{
    __shared__ u16 T[64 * 80];
    const int tid = threadIdx.x;
    const int bid = blockIdx.x;
    if (bid < 3072) {
        int t = bid >> 10;
        const float* src = (t == 0) ? q : (t == 1) ? k : v;
        u16* dst = (t == 0) ? qb : (t == 1) ? kb : vb;
        size_t base = (size_t)(bid & 1023) * 4096;
#pragma unroll
        for (int i = 0; i < 4; ++i) {
            size_t e = base + (size_t)(tid + i * 256) * 4;
            float4 xv = *(const float4*)(src + e);
            ushort4 o;
            o.x = f2bf(xv.x); o.y = f2bf(xv.y); o.z = f2bf(xv.z); o.w = f2bf(xv.w);
            *(ushort4*)(dst + e) = o;
        }
    } else {
        int wbid = bid - 3072;
        int w = wbid >> 8;
        const float* src = (w == 0) ? Wq : (w == 1) ? Wk : (w == 2) ? Wv : Wo;
        u16* dst = (w == 0) ? wqt : (w == 1) ? wkt : (w == 2) ? wvt : wot;
        int t = wbid & 255;
        int k0 = (t >> 4) * 64, nt0 = (t & 15) * 64;
#pragma unroll
        for (int i = 0; i < 4; ++i) {
            int f = tid + i * 256;
            int kk = f >> 4, nn = (f & 15) * 4;
            float4 xv = *(const float4*)(src + (size_t)(k0 + kk) * Dd + nt0 + nn);
            T[(nn + 0) * 80 + kk] = f2bf(xv.x);
            T[(nn + 1) * 80 + kk] = f2bf(xv.y);
            T[(nn + 2) * 80 + kk] = f2bf(xv.z);
            T[(nn + 3) * 80 + kk] = f2bf(xv.w);
        }
        __syncthreads();
#pragma unroll
        for (int i = 0; i < 2; ++i) {
            int g = tid + i * 256;
            int nn = g >> 3, k8 = (g & 7) * 8;
            *(uint4*)(dst + (size_t)(nt0 + nn) * Dd + k0 + k8) =
                *(const uint4*)&T[nn * 80 + k8];
        }
    }
}

// ---------------------------------------------------------------------------
// bf16 MFMA GEMM — R4/R5 version VERBATIM (WIN). QKV only (grid 1536 = 6/CU).
// R1 post-mortem (refined by R4): write-amplification came from TILE GROWTH
// register pressure, not gload_lds. Do not grow acc/fragment count.
// ---------------------------------------------------------------------------
__global__ __launch_bounds__(256)
void gemm_bf16(const u16* __restrict__ X0, const u16* __restrict__ X1,
               const u16* __restrict__ X2,
               const u16* __restrict__ W0, const u16* __restrict__ W1,
               const u16* __restrict__ W2,
               const float* __restrict__ b0, const float* __restrict__ b1,
               const float* __restrict__ b2,
               u16* __restrict__ O0, u16* __restrict__ O1, u16* __restrict__ O2,
               float* __restrict__ OutF, int fused)
{
    __shared__ u16 As[128 * 64];
    __shared__ u16 Bs[64 * 64];

    const int tid = threadIdx.x;
    const int wv = tid >> 6, lane = tid & 63, l16 = lane & 15, quad = lane >> 4;
    const int n0 = blockIdx.x * 64, m0 = blockIdx.y * 128;
    const int z = blockIdx.z;

    const u16* X      = fused ? ((z == 0) ? X0 : (z == 1) ? X1 : X2) : X0;
    const u16* Wt     = fused ? ((z == 0) ? W0 : (z == 1) ? W1 : W2) : W0;
    const float* bias = fused ? ((z == 0) ? b0 : (z == 1) ? b1 : b2) : b0;
    u16* OutB         = (z == 0) ? O0 : (z == 1) ? O1 : O2;
    const int mode    = fused ? ((z == 0) ? 1 : (z == 1) ? 3 : 2) : 0;

    const int srow = tid >> 3;            // p-chunk row 0..31
    const int scol = (tid & 7) * 8;

    frag_cd acc[2][4];
#pragma unroll
    for (int ms = 0; ms < 2; ++ms)
#pragma unroll
        for (int n = 0; n < 4; ++n) acc[ms][n] = (frag_cd){0.f, 0.f, 0.f, 0.f};

    for (int k0 = 0; k0 < Dd; k0 += 64) {
        __syncthreads();   // prev-iter LDS readers done
#pragma unroll
        for (int p = 0; p < 4; ++p)
            gload16(&X[(size_t)(m0 + p * 32 + srow) * Dd + k0 + scol],
                    &As[p * 2048 + wv * 512]);
#pragma unroll
        for (int p = 0; p < 2; ++p)
            gload16(&Wt[(size_t)(n0 + p * 32 + srow) * Dd + k0 + scol],
                    &Bs[p * 2048 + wv * 512]);
        __syncthreads();   // compiler drains vmcnt(0) here: staging complete

#pragma unroll
        for (int ks = 0; ks < 2; ++ks) {
            frag_ab a0 = *(const frag_ab*)&As[(wv * 32 + l16) * 64 + ks * 32 + quad * 8];
            frag_ab a1 = *(const frag_ab*)&As[(wv * 32 + 16 + l16) * 64 + ks * 32 + quad * 8];
#pragma unroll
            for (int n = 0; n < 4; ++n) {
                frag_ab b = *(const frag_ab*)&Bs[(n * 16 + l16) * 64 + ks * 32 + quad * 8];
                acc[0][n] = __builtin_amdgcn_mfma_f32_16x16x32_bf16(a0, b, acc[0][n], 0, 0, 0);
                acc[1][n] = __builtin_amdgcn_mfma_f32_16x16x32_bf16(a1, b, acc[1][n], 0, 0, 0);
            }
        }
    }

    float bv4[4];
#pragma unroll
    for (int n = 0; n < 4; ++n) bv4[n] = bias[n0 + n * 16 + l16];

    if (mode == 0) {
#pragma unroll
        for (int ms = 0; ms < 2; ++ms)
#pragma unroll
            for (int r = 0; r < 4; ++r) {
                int row = m0 + wv * 32 + ms * 16 + quad * 4 + r;
#pragma unroll
                for (int n = 0; n < 4; ++n)
                    OutF[(size_t)row * Dd + n0 + n * 16 + l16] = acc[ms][n][r] + bv4[n];
            }
    } else if (mode == 2) {
        const int h = n0 >> 6;
        const int b = m0 >> 11;
#pragma unroll
        for (int ms = 0; ms < 2; ++ms) {
            int sbase = (m0 & (Ss - 1)) + wv * 32 + ms * 16 + quad * 4;
#pragma unroll
            for (int n = 0; n < 4; ++n) {
                int d = n * 16 + l16;
                ushort4 o;
                o.x = f2bf(acc[ms][n][0] + bv4[n]);
                o.y = f2bf(acc[ms][n][1] + bv4[n]);
                o.z = f2bf(acc[ms][n][2] + bv4[n]);
                o.w = f2bf(acc[ms][n][3] + bv4[n]);
                *(ushort4*)&OutB[(((size_t)b * Hh + h) * DKk + d) * Ss + sbase] = o;
            }
        }
    } else {
        const int h = n0 >> 6;
        const float lg = 0.28782313662425575f;  // ln(10000)/32
        const float sc = (mode == 1) ? 0.125f : 1.0f;
#pragma unroll
        for (int ms = 0; ms < 2; ++ms)
#pragma unroll
            for (int r = 0; r < 4; ++r) {
                int row = m0 + wv * 32 + ms * 16 + quad * 4 + r;
                int b = row >> 11, s = row & (Ss - 1);
                u16* orow = OutB + (((size_t)b * Hh + h) * Ss + s) * DKk;
#pragma unroll
                for (int n = 0; n < 2; ++n) {
                    int j = n * 16 + l16;
                    float ang = (float)s * __expf(-(float)j * lg);
                    float cv = cosf(ang), sv = sinf(ang);
                    float lo = acc[ms][n][r] + bv4[n];
                    float hi = acc[ms][n + 2][r] + bv4[n + 2];
                    orow[j]      = f2bf((lo * cv - hi * sv) * sc);
                    orow[j + 32] = f2bf((hi * cv + lo * sv) * sc);
                }
            }
    }
}

// ---------------------------------------------------------------------------
// Out-projection GEMM — R7 version (neutral vs fused; kept: smaller footprint).
// ---------------------------------------------------------------------------
__global__ __launch_bounds__(256)
void gemm_out(const u16* __restrict__ X0, const u16* __restrict__ W0,
              const float* __restrict__ b0, float* __restrict__ OutF)
{
    __shared__ u16 As[64 * 64];
    __shared__ u16 Bs[64 * 64];

    const int tid = threadIdx.x;
    const int wv = tid >> 6, lane = tid & 63, l16 = lane & 15, quad = lane >> 4;
    const int n0 = blockIdx.x * 64, m0 = blockIdx.y * 64;

    const int srow = tid >> 3;            // p-chunk row 0..31
    const int scol = (tid & 7) * 8;

    frag_cd acc[4];
#pragma unroll
    for (int n = 0; n < 4; ++n) acc[n] = (frag_cd){0.f, 0.f, 0.f, 0.f};

    for (int k0 = 0; k0 < Dd; k0 += 64) {
        __syncthreads();   // prev-iter LDS readers done
#pragma unroll
        for (int p = 0; p < 2; ++p) {
            gload16(&X0[(size_t)(m0 + p * 32 + srow) * Dd + k0 + scol],
                    &As[p * 2048 + wv * 512]);
            gload16(&W0[(size_t)(n0 + p * 32 + srow) * Dd + k0 + scol],
                    &Bs[p * 2048 + wv * 512]);
        }
        __syncthreads();   // drains vmcnt(0): staging complete

#pragma unroll
        for (int ks = 0; ks < 2; ++ks) {
            frag_ab a0 = *(const frag_ab*)&As[(wv * 16 + l16) * 64 + ks * 32 + quad * 8];
#pragma unroll
            for (int n = 0; n < 4; ++n) {
                frag_ab b = *(const frag_ab*)&Bs[(n * 16 + l16) * 64 + ks * 32 + quad * 8];
                acc[n] = __builtin_amdgcn_mfma_f32_16x16x32_bf16(a0, b, acc[n], 0, 0, 0);
            }
        }
    }

    float bv4[4];
#pragma unroll
    for (int n = 0; n < 4; ++n) bv4[n] = b0[n0 + n * 16 + l16];

#pragma unroll
    for (int r = 0; r < 4; ++r) {
        int row = m0 + wv * 16 + quad * 4 + r;
#pragma unroll
        for (int n = 0; n < 4; ++n)
            OutF[(size_t)row * Dd + n0 + n * 16 + l16] = acc[n][r] + bv4[n];
    }
}

// ---------------------------------------------------------------------------
// MFMA flash attention — R8: T3-lite pipelining at ZERO register-staging cost.
//  * Q fragments live in registers (qreg[2], 8 VGPR) — Qs LDS tile deleted.
//  * Ks/Vs DOUBLE-buffered via gload_lds, ONE barrier per iteration:
//      barrier(kb) drains buf[cur] (issued last iter, latency hidden under
//      last iter's QK+softmax+PV); then issue buf[cur^1] for kb+1; compute.
//    Ordering: barrier(kb) also proves iter-(kb-1) readers of buf[cur^1]
//    finished (all waves arrived) => no WAR on the new issue. Ps wave-private.
//  * Ps -> [64][64] with the R6-PROVEN write/read XOR involution.
//  LDS = 2*8 + 2*8 + 8 = 40 KB exactly => 4 blocks/CU retained (4*40=160KiB).
//  R2 failure mode absent by construction: no staging VGPRs, no extra barrier.
// TRIPWIRES: LDS 40960; Occupancy ~25% (<=19% => 4x40KB didn't fit);
// dur>=75us => latency wasn't the binder, pivot to swapped-QK next.
// ---------------------------------------------------------------------------
__global__ __launch_bounds__(256)
void attn_mfma(const u16* __restrict__ Q, const u16* __restrict__ K,
               const u16* __restrict__ Vt, u16* __restrict__ Aout)
{
    __shared__ u16 Ks[2][64 * 64];
    __shared__ u16 Vs[2][64 * 64];
    __shared__ u16 Ps[64 * 64];

    const int tid = threadIdx.x;
    const int wv = tid >> 6;
    const int lane = tid & 63;
    const int l16 = lane & 15;
    const int quad = lane >> 4;

    const int bh = blockIdx.y;
    // balanced work swizzle: a CU's 4 resident blocks get qb summing to 66
    const int vsw = (blockIdx.x + (bh & 7)) & 31;
    const int jj  = bh >> 3;
    const int qb  = (jj == 0) ? vsw
                  : (jj == 1) ? ((vsw + 8) & 31)
                  : (jj == 2) ? ((23 - vsw) & 31)
                  :             (31 - vsw);
    const int q0 = qb * 64;

    const size_t qkbase = (size_t)bh * Ss * DKk;
    const size_t vbase  = (size_t)bh * DKk * Ss;
    const int b = bh >> 4, h = bh & 15;

    // staging geometry (gload_lds): lane -> (row = tid>>3 within 32-row chunk,
    // slot = tid&7). Source col pre-swizzled by row&7 (rule 21).
    const int srow = tid >> 3;                       // 0..31
    const int scol = ((tid & 7) ^ (srow & 7)) * 8;   // swizzled global col (u16)
    const int sx   = (l16 & 7) * 8;                  // read-side XOR (u16)

    // Q fragments straight to registers: row q0+wv*16+l16, cols h2*32+quad*8.
    frag_ab qreg[2];
    {
        const u16* qrow = &Q[qkbase + (size_t)(q0 + wv * 16 + l16) * DKk];
#pragma unroll
        for (int h2 = 0; h2 < 2; ++h2)
            qreg[h2] = *(const frag_ab*)&qrow[h2 * 32 + quad * 8];
    }

    // prologue: KV tile 0 -> buffer 0 (drained by the kb=0 barrier)
#pragma unroll
    for (int p = 0; p < 2; ++p) {
        gload16(&K[qkbase + (size_t)(p * 32 + srow) * DKk + scol],
                &Ks[0][p * 2048 + wv * 512]);
        gload16(&Vt[vbase + (size_t)(p * 32 + srow) * Ss + scol],
                &Vs[0][p * 2048 + wv * 512]);
    }

    float m_r[4], l_r[4];
#pragma unroll
    for (int r = 0; r < 4; ++r) { m_r[r] = -3.0e38f; l_r[r] = 0.f; }
    frag_cd of[4];
#pragma unroll
    for (int n = 0; n < 4; ++n) of[n] = (frag_cd){0.f, 0.f, 0.f, 0.f};

    for (int kb = 0; kb <= qb; ++kb) {
        const int cur = kb & 1;
        const u16* KsB = Ks[cur];
        const u16* VsB = Vs[cur];

        __syncthreads();   // drains vmcnt(0): buf[cur] staged; orders prev readers

        // issue NEXT tile's loads now; they drain at barrier(kb+1), with this
        // whole iteration's compute in between => latency hidden.
        if (kb < qb) {
            const int k0n = (kb + 1) * 64;
#pragma unroll
            for (int p = 0; p < 2; ++p) {
                gload16(&K[qkbase + (size_t)(k0n + p * 32 + srow) * DKk + scol],
                        &Ks[cur ^ 1][p * 2048 + wv * 512]);
                gload16(&Vt[vbase + (size_t)(p * 32 + srow) * Ss + k0n + scol],
                        &Vs[cur ^ 1][p * 2048 + wv * 512]);
            }
        }

        frag_cd sf[4];
#pragma unroll
        for (int n = 0; n < 4; ++n) sf[n] = (frag_cd){0.f, 0.f, 0.f, 0.f};
#pragma unroll
        for (int h2 = 0; h2 < 2; ++h2) {
#pragma unroll
            for (int n = 0; n < 4; ++n) {
                frag_ab kf = *(const frag_ab*)&KsB[(n * 16 + l16) * 64 + ((h2 * 32 + quad * 8) ^ sx)];
                sf[n] = __builtin_amdgcn_mfma_f32_16x16x32_bf16(qreg[h2], kf, sf[n], 0, 0, 0);
            }
        }

        if (kb == qb) {
#pragma unroll
            for (int r = 0; r < 4; ++r) {
                int qi = wv * 16 + quad * 4 + r;
#pragma unroll
                for (int n = 0; n < 4; ++n)
                    if (n * 16 + l16 > qi) sf[n][r] = -1.0e30f;
            }
        }

        float alpha[4];
#pragma unroll
        for (int r = 0; r < 4; ++r) {
            float mx = m_r[r];
#pragma unroll
            for (int n = 0; n < 4; ++n) mx = fmaxf(mx, sf[n][r]);
#pragma unroll
            for (int off = 1; off < 16; off <<= 1) mx = fmaxf(mx, __shfl_xor(mx, off));
            float a = __expf(m_r[r] - mx);
            m_r[r] = mx;
            float sum = 0.f;
#pragma unroll
            for (int n = 0; n < 4; ++n) {
                float p = __expf(sf[n][r] - mx);
                sf[n][r] = p;
                sum += p;
            }
#pragma unroll
            for (int off = 1; off < 16; off <<= 1) sum += __shfl_xor(sum, off);
            l_r[r] = l_r[r] * a + sum;
            alpha[r] = a;
        }
#pragma unroll
        for (int n = 0; n < 4; ++n)
#pragma unroll
            for (int r = 0; r < 4; ++r) of[n][r] *= alpha[r];

        // P -> LDS, swizzled (R6-proven involution)
#pragma unroll
        for (int n = 0; n < 4; ++n)
#pragma unroll
            for (int r = 0; r < 4; ++r) {
                int row = wv * 16 + quad * 4 + r;
                Ps[row * 64 + ((n * 16 + l16) ^ ((row & 7) << 3))] = f2bf(sf[n][r]);
            }
        __threadfence_block();   // wave-private P strip: intra-wave order only

#pragma unroll
        for (int h2 = 0; h2 < 2; ++h2) {
            frag_ab pa = *(const frag_ab*)&Ps[(wv * 16 + l16) * 64 + ((h2 * 32 + quad * 8) ^ sx)];
#pragma unroll
            for (int n = 0; n < 4; ++n) {
                frag_ab vf = *(const frag_ab*)&VsB[(n * 16 + l16) * 64 + ((h2 * 32 + quad * 8) ^ sx)];
                of[n] = __builtin_amdgcn_mfma_f32_16x16x32_bf16(pa, vf, of[n], 0, 0, 0);
            }
        }
    }

#pragma unroll
    for (int r = 0; r < 4; ++r) {
        float inv = 1.f / l_r[r];
        int row = q0 + wv * 16 + quad * 4 + r;
        u16* orow = Aout + ((size_t)b * Ss + row) * Dd + h * DKk;
#pragma unroll
        for (int n = 0; n < 4; ++n) orow[n * 16 + l16] = f2bf(of[n][r] * inv);
    }
}

extern "C" void kernel_launch(void* const* d_in, const int* in_sizes, int n_in,
                              void* d_out, int out_size, void* d_ws, size_t ws_size,
                              hipStream_t stream) {
    (void)in_sizes; (void)n_in; (void)out_size;
    const float* q  = (const float*)d_in[0];
    const float* k  = (const float*)d_in[1];
    const float* v  = (const float*)d_in[2];
    // d_in[3] = mask (tril causal) -- enforced analytically in attn_mfma
    const float* Wq = (const float*)d_in[4];
    const float* bq = (const float*)d_in[5];
    const float* Wk = (const float*)d_in[6];
    const float* bk = (const float*)d_in[7];
    const float* Wv = (const float*)d_in[8];
    const float* bv = (const float*)d_in[9];
    const float* Wo = (const float*)d_in[10];
    const float* bo = (const float*)d_in[11];
    float* out = (float*)d_out;

    const size_t E = (size_t)Bb * Ss * Dd;     // 4,194,304
    const size_t Wn = (size_t)Dd * Dd;         // 1,048,576
    const size_t need = (7 * E + 4 * Wn) * sizeof(u16);   // 64 MiB
    if (ws_size < need) return;
    u16* qa  = (u16*)d_ws;
    u16* ka  = qa + E;
    u16* va  = ka + E;
    u16* wqt = va + E;
    u16* wkt = wqt + Wn;
    u16* wvt = wkt + Wn;
    u16* wot = wvt + Wn;
    u16* Qh  = wot + Wn;
    u16* Kh  = Qh + E;
    u16* Vth = Kh + E;
    u16* Abf = Vth + E;

    convert_kernel<<<4096, 256, 0, stream>>>(q, k, v, Wq, Wk, Wv, Wo,
                                             qa, ka, va, wqt, wkt, wvt, wot);
    gemm_bf16<<<dim3(Dd / 64, BSn / 128, 3), 256, 0, stream>>>(
        qa, ka, va, wqt, wkt, wvt, bq, bk, bv, Qh, Kh, Vth, nullptr, 1);
    attn_mfma<<<dim3(32, Bb * Hh), 256, 0, stream>>>(Qh, Kh, Vth, Abf);
    gemm_out<<<dim3(Dd / 64, BSn / 64), 256, 0, stream>>>(Abf, wot, bo, out);
}

// Round 9
// 268.637 us; speedup vs baseline: 1.0422x; 1.0214x over previous
//
#include <hip/hip_runtime.h>
#include <hip/hip_bf16.h>
#include <math.h>

#define Bb 2
#define Ss 2048
#define Dd 1024
#define Hh 16
#define DKk 64
#define BSn (Bb*Ss)

typedef unsigned short u16;
typedef __attribute__((ext_vector_type(8))) short frag_ab;   // 8 bf16
typedef __attribute__((ext_vector_type(4))) float frag_cd;   // 4 f32

static __device__ __forceinline__ u16 f2bf(float x) {
    __hip_bfloat16 h = __float2bfloat16(x);
    return *reinterpret_cast<u16*>(&h);
}

// Direct global->LDS async copy, 16B per lane. LDS dest is the wave-uniform
// base; HW writes lane i at base + i*16B. Requires LINEAR (unpadded) LDS.
static __device__ __forceinline__ void gload16(const u16* g, u16* l) {
    __builtin_amdgcn_global_load_lds(
        (const __attribute__((address_space(1))) void*)g,
        (__attribute__((address_space(3))) void*)l, 16, 0, 0);
}

// ---------------------------------------------------------------------------
// One-shot convert: q,k,v fp32 -> bf16; W* fp32 [k][n] -> bf16 transposed [n][k].
// ---------------------------------------------------------------------------
__global__ __launch_bounds__(256)
void convert_kernel(const float* __restrict__ q, const float* __restrict__ k,
                    const float* __restrict__ v,
                    const float* __restrict__ Wq, const float* __restrict__ Wk,
                    const float* __restrict__ Wv, const float* __restrict__ Wo,
                    u16* __restrict__ qb, u16* __restrict__ kb, u16* __restrict__ vb,
                    u16* __restrict__ wqt, u16* __restrict__ wkt,
                    u16* __restrict__ wvt, u16* __restrict__ wot)
{
    __shared__ u16 T[64 * 80];
    const int tid = threadIdx.x;
    const int bid = blockIdx.x;
    if (bid < 3072) {
        int t = bid >> 10;
        const float* src = (t == 0) ? q : (t == 1) ? k : v;
        u16* dst = (t == 0) ? qb : (t == 1) ? kb : vb;
        size_t base = (size_t)(bid & 1023) * 4096;
#pragma unroll
        for (int i = 0; i < 4; ++i) {
            size_t e = base + (size_t)(tid + i * 256) * 4;
            float4 xv = *(const float4*)(src + e);
            ushort4 o;
            o.x = f2bf(xv.x); o.y = f2bf(xv.y); o.z = f2bf(xv.z); o.w = f2bf(xv.w);
            *(ushort4*)(dst + e) = o;
        }
    } else {
        int wbid = bid - 3072;
        int w = wbid >> 8;
        const float* src = (w == 0) ? Wq : (w == 1) ? Wk : (w == 2) ? Wv : Wo;
        u16* dst = (w == 0) ? wqt : (w == 1) ? wkt : (w == 2) ? wvt : wot;
        int t = wbid & 255;
        int k0 = (t >> 4) * 64, nt0 = (t & 15) * 64;
#pragma unroll
        for (int i = 0; i < 4; ++i) {
            int f = tid + i * 256;
            int kk = f >> 4, nn = (f & 15) * 4;
            float4 xv = *(const float4*)(src + (size_t)(k0 + kk) * Dd + nt0 + nn);
            T[(nn + 0) * 80 + kk] = f2bf(xv.x);
            T[(nn + 1) * 80 + kk] = f2bf(xv.y);
            T[(nn + 2) * 80 + kk] = f2bf(xv.z);
            T[(nn + 3) * 80 + kk] = f2bf(xv.w);
        }
        __syncthreads();
#pragma unroll
        for (int i = 0; i < 2; ++i) {
            int g = tid + i * 256;
            int nn = g >> 3, k8 = (g & 7) * 8;
            *(uint4*)(dst + (size_t)(nt0 + nn) * Dd + k0 + k8) =
                *(const uint4*)&T[nn * 80 + k8];
        }
    }
}

// ---------------------------------------------------------------------------
// bf16 MFMA GEMM — R4/R5 version VERBATIM (WIN). QKV only (grid 1536 = 6/CU).
// R1 post-mortem (refined by R4): write-amplification came from TILE GROWTH
// register pressure, not gload_lds. Do not grow acc/fragment count.
// ---------------------------------------------------------------------------
__global__ __launch_bounds__(256)
void gemm_bf16(const u16* __restrict__ X0, const u16* __restrict__ X1,
               const u16* __restrict__ X2,
               const u16* __restrict__ W0, const u16* __restrict__ W1,
               const u16* __restrict__ W2,
               const float* __restrict__ b0, const float* __restrict__ b1,
               const float* __restrict__ b2,
               u16* __restrict__ O0, u16* __restrict__ O1, u16* __restrict__ O2,
               float* __restrict__ OutF, int fused)
{
    __shared__ u16 As[128 * 64];
    __shared__ u16 Bs[64 * 64];

    const int tid = threadIdx.x;
    const int wv = tid >> 6, lane = tid & 63, l16 = lane & 15, quad = lane >> 4;
    const int n0 = blockIdx.x * 64, m0 = blockIdx.y * 128;
    const int z = blockIdx.z;

    const u16* X      = fused ? ((z == 0) ? X0 : (z == 1) ? X1 : X2) : X0;
    const u16* Wt     = fused ? ((z == 0) ? W0 : (z == 1) ? W1 : W2) : W0;
    const float* bias = fused ? ((z == 0) ? b0 : (z == 1) ? b1 : b2) : b0;
    u16* OutB         = (z == 0) ? O0 : (z == 1) ? O1 : O2;
    const int mode    = fused ? ((z == 0) ? 1 : (z == 1) ? 3 : 2) : 0;

    const int srow = tid >> 3;            // p-chunk row 0..31
    const int scol = (tid & 7) * 8;

    frag_cd acc[2][4];
#pragma unroll
    for (int ms = 0; ms < 2; ++ms)
#pragma unroll
        for (int n = 0; n < 4; ++n) acc[ms][n] = (frag_cd){0.f, 0.f, 0.f, 0.f};

    for (int k0 = 0; k0 < Dd; k0 += 64) {
        __syncthreads();   // prev-iter LDS readers done
#pragma unroll
        for (int p = 0; p < 4; ++p)
            gload16(&X[(size_t)(m0 + p * 32 + srow) * Dd + k0 + scol],
                    &As[p * 2048 + wv * 512]);
#pragma unroll
        for (int p = 0; p < 2; ++p)
            gload16(&Wt[(size_t)(n0 + p * 32 + srow) * Dd + k0 + scol],
                    &Bs[p * 2048 + wv * 512]);
        __syncthreads();   // compiler drains vmcnt(0) here: staging complete

#pragma unroll
        for (int ks = 0; ks < 2; ++ks) {
            frag_ab a0 = *(const frag_ab*)&As[(wv * 32 + l16) * 64 + ks * 32 + quad * 8];
            frag_ab a1 = *(const frag_ab*)&As[(wv * 32 + 16 + l16) * 64 + ks * 32 + quad * 8];
#pragma unroll
            for (int n = 0; n < 4; ++n) {
                frag_ab b = *(const frag_ab*)&Bs[(n * 16 + l16) * 64 + ks * 32 + quad * 8];
                acc[0][n] = __builtin_amdgcn_mfma_f32_16x16x32_bf16(a0, b, acc[0][n], 0, 0, 0);
                acc[1][n] = __builtin_amdgcn_mfma_f32_16x16x32_bf16(a1, b, acc[1][n], 0, 0, 0);
            }
        }
    }

    float bv4[4];
#pragma unroll
    for (int n = 0; n < 4; ++n) bv4[n] = bias[n0 + n * 16 + l16];

    if (mode == 0) {
#pragma unroll
        for (int ms = 0; ms < 2; ++ms)
#pragma unroll
            for (int r = 0; r < 4; ++r) {
                int row = m0 + wv * 32 + ms * 16 + quad * 4 + r;
#pragma unroll
                for (int n = 0; n < 4; ++n)
                    OutF[(size_t)row * Dd + n0 + n * 16 + l16] = acc[ms][n][r] + bv4[n];
            }
    } else if (mode == 2) {
        const int h = n0 >> 6;
        const int b = m0 >> 11;
#pragma unroll
        for (int ms = 0; ms < 2; ++ms) {
            int sbase = (m0 & (Ss - 1)) + wv * 32 + ms * 16 + quad * 4;
#pragma unroll
            for (int n = 0; n < 4; ++n) {
                int d = n * 16 + l16;
                ushort4 o;
                o.x = f2bf(acc[ms][n][0] + bv4[n]);
                o.y = f2bf(acc[ms][n][1] + bv4[n]);
                o.z = f2bf(acc[ms][n][2] + bv4[n]);
                o.w = f2bf(acc[ms][n][3] + bv4[n]);
                *(ushort4*)&OutB[(((size_t)b * Hh + h) * DKk + d) * Ss + sbase] = o;
            }
        }
    } else {
        const int h = n0 >> 6;
        const float lg = 0.28782313662425575f;  // ln(10000)/32
        const float sc = (mode == 1) ? 0.125f : 1.0f;
#pragma unroll
        for (int ms = 0; ms < 2; ++ms)
#pragma unroll
            for (int r = 0; r < 4; ++r) {
                int row = m0 + wv * 32 + ms * 16 + quad * 4 + r;
                int b = row >> 11, s = row & (Ss - 1);
                u16* orow = OutB + (((size_t)b * Hh + h) * Ss + s) * DKk;
#pragma unroll
                for (int n = 0; n < 2; ++n) {
                    int j = n * 16 + l16;
                    float ang = (float)s * __expf(-(float)j * lg);
                    float cv = cosf(ang), sv = sinf(ang);
                    float lo = acc[ms][n][r] + bv4[n];
                    float hi = acc[ms][n + 2][r] + bv4[n + 2];
                    orow[j]      = f2bf((lo * cv - hi * sv) * sc);
                    orow[j + 32] = f2bf((hi * cv + lo * sv) * sc);
                }
            }
    }
}

// ---------------------------------------------------------------------------
// Out-projection GEMM — R7 version (neutral vs fused; kept: smaller footprint).
// ---------------------------------------------------------------------------
__global__ __launch_bounds__(256)
void gemm_out(const u16* __restrict__ X0, const u16* __restrict__ W0,
              const float* __restrict__ b0, float* __restrict__ OutF)
{
    __shared__ u16 As[64 * 64];
    __shared__ u16 Bs[64 * 64];

    const int tid = threadIdx.x;
    const int wv = tid >> 6, lane = tid & 63, l16 = lane & 15, quad = lane >> 4;
    const int n0 = blockIdx.x * 64, m0 = blockIdx.y * 64;

    const int srow = tid >> 3;            // p-chunk row 0..31
    const int scol = (tid & 7) * 8;

    frag_cd acc[4];
#pragma unroll
    for (int n = 0; n < 4; ++n) acc[n] = (frag_cd){0.f, 0.f, 0.f, 0.f};

    for (int k0 = 0; k0 < Dd; k0 += 64) {
        __syncthreads();   // prev-iter LDS readers done
#pragma unroll
        for (int p = 0; p < 2; ++p) {
            gload16(&X0[(size_t)(m0 + p * 32 + srow) * Dd + k0 + scol],
                    &As[p * 2048 + wv * 512]);
            gload16(&W0[(size_t)(n0 + p * 32 + srow) * Dd + k0 + scol],
                    &Bs[p * 2048 + wv * 512]);
        }
        __syncthreads();   // drains vmcnt(0): staging complete

#pragma unroll
        for (int ks = 0; ks < 2; ++ks) {
            frag_ab a0 = *(const frag_ab*)&As[(wv * 16 + l16) * 64 + ks * 32 + quad * 8];
#pragma unroll
            for (int n = 0; n < 4; ++n) {
                frag_ab b = *(const frag_ab*)&Bs[(n * 16 + l16) * 64 + ks * 32 + quad * 8];
                acc[n] = __builtin_amdgcn_mfma_f32_16x16x32_bf16(a0, b, acc[n], 0, 0, 0);
            }
        }
    }

    float bv4[4];
#pragma unroll
    for (int n = 0; n < 4; ++n) bv4[n] = b0[n0 + n * 16 + l16];

#pragma unroll
    for (int r = 0; r < 4; ++r) {
        int row = m0 + wv * 16 + quad * 4 + r;
#pragma unroll
        for (int n = 0; n < 4; ++n)
            OutF[(size_t)row * Dd + n0 + n * 16 + l16] = acc[n][r] + bv4[n];
    }
}

// ---------------------------------------------------------------------------
// MFMA flash attention — R9: SWAPPED-QK^T softmax (T12-lite) on the R8 frame.
//  * sf[n] = mfma(kf, qreg) (operands swapped, identical LDS reads) =>
//    lane (quad,l16) holds S[q = wv*16+l16][k = n*16+quad*4+r]: the whole
//    softmax row is LANE-LOCAL. m/l are per-lane scalars.
//  * Row reduce: 5-deep fmax/add tree + TWO shfl_xor (16,32) quad-combines
//    (was 4x 4-step reduces = 32 shuffles; now 8 total: the serial chain
//    that R8 proved is the binder).
//  * P-write: 4x ushort4 (was 16 scalar u16) into the R8 Ps[64x64] XOR
//    involution (XOR hits col bits 3-5; ushort4 spans bits 0-1 => intact).
//  * Mask: k>q per-reg: n*16+quad*4+r > wv*16+l16 (diag tile only).
//  * alpha / 1/l broadcast back to C-layout rows via 4 __shfl each.
//  Staging/dbuf/grid/LDS(40KB,4 blocks/CU) unchanged from R8.
// TRIPWIRES: absmax 0.0078125 (swap bug => blowup); dur>=74us => chain not
// softmax-bound, pivot to KVBLK=128 next.
// ---------------------------------------------------------------------------
__global__ __launch_bounds__(256)
void attn_mfma(const u16* __restrict__ Q, const u16* __restrict__ K,
               const u16* __restrict__ Vt, u16* __restrict__ Aout)
{
    __shared__ u16 Ks[2][64 * 64];
    __shared__ u16 Vs[2][64 * 64];
    __shared__ u16 Ps[64 * 64];

    const int tid = threadIdx.x;
    const int wv = tid >> 6;
    const int lane = tid & 63;
    const int l16 = lane & 15;
    const int quad = lane >> 4;

    const int bh = blockIdx.y;
    // balanced work swizzle: a CU's 4 resident blocks get qb summing to 66
    const int vsw = (blockIdx.x + (bh & 7)) & 31;
    const int jj  = bh >> 3;
    const int qb  = (jj == 0) ? vsw
                  : (jj == 1) ? ((vsw + 8) & 31)
                  : (jj == 2) ? ((23 - vsw) & 31)
                  :             (31 - vsw);
    const int q0 = qb * 64;

    const size_t qkbase = (size_t)bh * Ss * DKk;
    const size_t vbase  = (size_t)bh * DKk * Ss;
    const int b = bh >> 4, h = bh & 15;

    // staging geometry (gload_lds): lane -> (row = tid>>3 within 32-row chunk,
    // slot = tid&7). Source col pre-swizzled by row&7 (rule 21).
    const int srow = tid >> 3;                       // 0..31
    const int scol = ((tid & 7) ^ (srow & 7)) * 8;   // swizzled global col (u16)
    const int sx   = (l16 & 7) * 8;                  // read-side XOR (u16)

    // Q fragments straight to registers: row q0+wv*16+l16, cols h2*32+quad*8.
    frag_ab qreg[2];
    {
        const u16* qrow = &Q[qkbase + (size_t)(q0 + wv * 16 + l16) * DKk];
#pragma unroll
        for (int h2 = 0; h2 < 2; ++h2)
            qreg[h2] = *(const frag_ab*)&qrow[h2 * 32 + quad * 8];
    }

    // prologue: KV tile 0 -> buffer 0 (drained by the kb=0 barrier)
#pragma unroll
    for (int p = 0; p < 2; ++p) {
        gload16(&K[qkbase + (size_t)(p * 32 + srow) * DKk + scol],
                &Ks[0][p * 2048 + wv * 512]);
        gload16(&Vt[vbase + (size_t)(p * 32 + srow) * Ss + scol],
                &Vs[0][p * 2048 + wv * 512]);
    }

    float m_r = -3.0e38f, l_r = 0.f;     // per-lane: q = wv*16 + l16
    frag_cd of[4];
#pragma unroll
    for (int n = 0; n < 4; ++n) of[n] = (frag_cd){0.f, 0.f, 0.f, 0.f};

    for (int kb = 0; kb <= qb; ++kb) {
        const int cur = kb & 1;
        const u16* KsB = Ks[cur];
        const u16* VsB = Vs[cur];

        __syncthreads();   // drains vmcnt(0): buf[cur] staged; orders prev readers

        // issue NEXT tile's loads now; they drain at barrier(kb+1)
        if (kb < qb) {
            const int k0n = (kb + 1) * 64;
#pragma unroll
            for (int p = 0; p < 2; ++p) {
                gload16(&K[qkbase + (size_t)(k0n + p * 32 + srow) * DKk + scol],
                        &Ks[cur ^ 1][p * 2048 + wv * 512]);
                gload16(&Vt[vbase + (size_t)(p * 32 + srow) * Ss + k0n + scol],
                        &Vs[cur ^ 1][p * 2048 + wv * 512]);
            }
        }

        // QK^T, SWAPPED: sf[n][r] = S[q = wv*16+l16][k = n*16+quad*4+r]
        frag_cd sf[4];
#pragma unroll
        for (int n = 0; n < 4; ++n) sf[n] = (frag_cd){0.f, 0.f, 0.f, 0.f};
#pragma unroll
        for (int h2 = 0; h2 < 2; ++h2) {
#pragma unroll
            for (int n = 0; n < 4; ++n) {
                frag_ab kf = *(const frag_ab*)&KsB[(n * 16 + l16) * 64 + ((h2 * 32 + quad * 8) ^ sx)];
                sf[n] = __builtin_amdgcn_mfma_f32_16x16x32_bf16(kf, qreg[h2], sf[n], 0, 0, 0);
            }
        }

        if (kb == qb) {
            const int qloc = wv * 16 + l16;
#pragma unroll
            for (int n = 0; n < 4; ++n)
#pragma unroll
                for (int r = 0; r < 4; ++r)
                    if (n * 16 + quad * 4 + r > qloc) sf[n][r] = -1.0e30f;
        }

        // --- lane-local row softmax ---
        // max: 5-deep tree over 16 regs, then 2 quad-combine shuffles
        frag_cd t0, t1;
#pragma unroll
        for (int r = 0; r < 4; ++r) {
            t0[r] = fmaxf(sf[0][r], sf[1][r]);
            t1[r] = fmaxf(sf[2][r], sf[3][r]);
        }
        float mx = fmaxf(fmaxf(fmaxf(t0[0], t1[0]), fmaxf(t0[1], t1[1])),
                         fmaxf(fmaxf(t0[2], t1[2]), fmaxf(t0[3], t1[3])));
        mx = fmaxf(mx, m_r);
        mx = fmaxf(mx, __shfl_xor(mx, 16));
        mx = fmaxf(mx, __shfl_xor(mx, 32));

        float a = __expf(m_r - mx);
        m_r = mx;

        // exp + sum tree
        frag_cd s0, s1;
#pragma unroll
        for (int n = 0; n < 4; ++n)
#pragma unroll
            for (int r = 0; r < 4; ++r)
                sf[n][r] = __expf(sf[n][r] - mx);
#pragma unroll
        for (int r = 0; r < 4; ++r) {
            s0[r] = sf[0][r] + sf[1][r];
            s1[r] = sf[2][r] + sf[3][r];
        }
        float sum = ((s0[0] + s1[0]) + (s0[1] + s1[1])) +
                    ((s0[2] + s1[2]) + (s0[3] + s1[3]));
        sum += __shfl_xor(sum, 16);
        sum += __shfl_xor(sum, 32);
        l_r = l_r * a + sum;

        // broadcast alpha to C-layout rows (of[n][r] is q = wv*16+quad*4+r)
        float a4[4];
#pragma unroll
        for (int r = 0; r < 4; ++r)
            a4[r] = __shfl(a, (lane & 48) | (quad * 4 + r));
#pragma unroll
        for (int n = 0; n < 4; ++n)
#pragma unroll
            for (int r = 0; r < 4; ++r) of[n][r] *= a4[r];

        // P -> LDS: 4x ushort4 into the swizzled [64][64] (R8 involution)
        {
            const int prow = wv * 16 + l16;
            const int px8  = (l16 & 7) << 3;
#pragma unroll
            for (int n = 0; n < 4; ++n) {
                ushort4 o;
                o.x = f2bf(sf[n][0]); o.y = f2bf(sf[n][1]);
                o.z = f2bf(sf[n][2]); o.w = f2bf(sf[n][3]);
                *(ushort4*)&Ps[prow * 64 + ((n * 16 + quad * 4) ^ px8)] = o;
            }
        }
        __threadfence_block();   // wave-private P strip: intra-wave order only

#pragma unroll
        for (int h2 = 0; h2 < 2; ++h2) {
            frag_ab pa = *(const frag_ab*)&Ps[(wv * 16 + l16) * 64 + ((h2 * 32 + quad * 8) ^ sx)];
#pragma unroll
            for (int n = 0; n < 4; ++n) {
                frag_ab vf = *(const frag_ab*)&VsB[(n * 16 + l16) * 64 + ((h2 * 32 + quad * 8) ^ sx)];
                of[n] = __builtin_amdgcn_mfma_f32_16x16x32_bf16(pa, vf, of[n], 0, 0, 0);
            }
        }
    }

    // epilogue: 1/l lives at lane l16=q; broadcast to C-layout rows
    float linv = 1.f / l_r;
    float inv4[4];
#pragma unroll
    for (int r = 0; r < 4; ++r)
        inv4[r] = __shfl(linv, (lane & 48) | (quad * 4 + r));

#pragma unroll
    for (int r = 0; r < 4; ++r) {
        int row = q0 + wv * 16 + quad * 4 + r;
        u16* orow = Aout + ((size_t)b * Ss + row) * Dd + h * DKk;
#pragma unroll
        for (int n = 0; n < 4; ++n) orow[n * 16 + l16] = f2bf(of[n][r] * inv4[r]);
    }
}

extern "C" void kernel_launch(void* const* d_in, const int* in_sizes, int n_in,
                              void* d_out, int out_size, void* d_ws, size_t ws_size,
                              hipStream_t stream) {
    (void)in_sizes; (void)n_in; (void)out_size;
    const float* q  = (const float*)d_in[0];
    const float* k  = (const float*)d_in[1];
    const float* v  = (const float*)d_in[2];
    // d_in[3] = mask (tril causal) -- enforced analytically in attn_mfma
    const float* Wq = (const float*)d_in[4];
    const float* bq = (const float*)d_in[5];
    const float* Wk = (const float*)d_in[6];
    const float* bk = (const float*)d_in[7];
    const float* Wv = (const float*)d_in[8];
    const float* bv = (const float*)d_in[9];
    const float* Wo = (const float*)d_in[10];
    const float* bo = (const float*)d_in[11];
    float* out = (float*)d_out;

    const size_t E = (size_t)Bb * Ss * Dd;     // 4,194,304
    const size_t Wn = (size_t)Dd * Dd;         // 1,048,576
    const size_t need = (7 * E + 4 * Wn) * sizeof(u16);   // 64 MiB
    if (ws_size < need) return;
    u16* qa  = (u16*)d_ws;
    u16* ka  = qa + E;
    u16* va  = ka + E;
    u16* wqt = va + E;
    u16* wkt = wqt + Wn;
    u16* wvt = wkt + Wn;
    u16* wot = wvt + Wn;
    u16* Qh  = wot + Wn;
    u16* Kh  = Qh + E;
    u16* Vth = Kh + E;
    u16* Abf = Vth + E;

    convert_kernel<<<4096, 256, 0, stream>>>(q, k, v, Wq, Wk, Wv, Wo,
                                             qa, ka, va, wqt, wkt, wvt, wot);
    gemm_bf16<<<dim3(Dd / 64, BSn / 128, 3), 256, 0, stream>>>(
        qa, ka, va, wqt, wkt, wvt, bq, bk, bv, Qh, Kh, Vth, nullptr, 1);
    attn_mfma<<<dim3(32, Bb * Hh), 256, 0, stream>>>(Qh, Kh, Vth, Abf);
    gemm_out<<<dim3(Dd / 64, BSn / 64), 256, 0, stream>>>(Abf, wot, bo, out);
}

// Round 10
// 262.394 us; speedup vs baseline: 1.0670x; 1.0238x over previous
//
#include <hip/hip_runtime.h>
#include <hip/hip_bf16.h>
#include <math.h>

#define Bb 2
#define Ss 2048
#define Dd 1024
#define Hh 16
#define DKk 64
#define BSn (Bb*Ss)

typedef unsigned short u16;
typedef __attribute__((ext_vector_type(8))) short frag_ab;   // 8 bf16
typedef __attribute__((ext_vector_type(4))) float frag_cd;   // 4 f32

static __device__ __forceinline__ u16 f2bf(float x) {
    __hip_bfloat16 h = __float2bfloat16(x);
    return *reinterpret_cast<u16*>(&h);
}

// Direct global->LDS async copy, 16B per lane. LDS dest is the wave-uniform
// base; HW writes lane i at base + i*16B. Requires LINEAR (unpadded) LDS.
static __device__ __forceinline__ void gload16(const u16* g, u16* l) {
    __builtin_amdgcn_global_load_lds(
        (const __attribute__((address_space(1))) void*)g,
        (__attribute__((address_space(3))) void*)l, 16, 0, 0);
}

// ---------------------------------------------------------------------------
// One-shot convert: q,k,v fp32 -> bf16; W* fp32 [k][n] -> bf16 transposed [n][k].
// ---------------------------------------------------------------------------
__global__ __launch_bounds__(256)
void convert_kernel(const float* __restrict__ q, const float* __restrict__ k,
                    const float* __restrict__ v,
                    const float* __restrict__ Wq, const float* __restrict__ Wk,
                    const float* __restrict__ Wv, const float* __restrict__ Wo,
                    u16* __restrict__ qb, u16* __restrict__ kb, u16* __restrict__ vb,
                    u16* __restrict__ wqt, u16* __restrict__ wkt,
                    u16* __restrict__ wvt, u16* __restrict__ wot)
{
    __shared__ u16 T[64 * 80];
    const int tid = threadIdx.x;
    const int bid = blockIdx.x;
    if (bid < 3072) {
        int t = bid >> 10;
        const float* src = (t == 0) ? q : (t == 1) ? k : v;
        u16* dst = (t == 0) ? qb : (t == 1) ? kb : vb;
        size_t base = (size_t)(bid & 1023) * 4096;
#pragma unroll
        for (int i = 0; i < 4; ++i) {
            size_t e = base + (size_t)(tid + i * 256) * 4;
            float4 xv = *(const float4*)(src + e);
            ushort4 o;
            o.x = f2bf(xv.x); o.y = f2bf(xv.y); o.z = f2bf(xv.z); o.w = f2bf(xv.w);
            *(ushort4*)(dst + e) = o;
        }
    } else {
        int wbid = bid - 3072;
        int w = wbid >> 8;
        const float* src = (w == 0) ? Wq : (w == 1) ? Wk : (w == 2) ? Wv : Wo;
        u16* dst = (w == 0) ? wqt : (w == 1) ? wkt : (w == 2) ? wvt : wot;
        int t = wbid & 255;
        int k0 = (t >> 4) * 64, nt0 = (t & 15) * 64;
#pragma unroll
        for (int i = 0; i < 4; ++i) {
            int f = tid + i * 256;
            int kk = f >> 4, nn = (f & 15) * 4;
            float4 xv = *(const float4*)(src + (size_t)(k0 + kk) * Dd + nt0 + nn);
            T[(nn + 0) * 80 + kk] = f2bf(xv.x);
            T[(nn + 1) * 80 + kk] = f2bf(xv.y);
            T[(nn + 2) * 80 + kk] = f2bf(xv.z);
            T[(nn + 3) * 80 + kk] = f2bf(xv.w);
        }
        __syncthreads();
#pragma unroll
        for (int i = 0; i < 2; ++i) {
            int g = tid + i * 256;
            int nn = g >> 3, k8 = (g & 7) * 8;
            *(uint4*)(dst + (size_t)(nt0 + nn) * Dd + k0 + k8) =
                *(const uint4*)&T[nn * 80 + k8];
        }
    }
}

// ---------------------------------------------------------------------------
// bf16 MFMA GEMM — R4/R5 version VERBATIM (WIN). QKV only (grid 1536 = 6/CU).
// R1 post-mortem (refined by R4): write-amplification came from TILE GROWTH
// register pressure, not gload_lds. Do not grow acc/fragment count.
// ---------------------------------------------------------------------------
__global__ __launch_bounds__(256)
void gemm_bf16(const u16* __restrict__ X0, const u16* __restrict__ X1,
               const u16* __restrict__ X2,
               const u16* __restrict__ W0, const u16* __restrict__ W1,
               const u16* __restrict__ W2,
               const float* __restrict__ b0, const float* __restrict__ b1,
               const float* __restrict__ b2,
               u16* __restrict__ O0, u16* __restrict__ O1, u16* __restrict__ O2,
               float* __restrict__ OutF, int fused)
{
    __shared__ u16 As[128 * 64];
    __shared__ u16 Bs[64 * 64];

    const int tid = threadIdx.x;
    const int wv = tid >> 6, lane = tid & 63, l16 = lane & 15, quad = lane >> 4;
    const int n0 = blockIdx.x * 64, m0 = blockIdx.y * 128;
    const int z = blockIdx.z;

    const u16* X      = fused ? ((z == 0) ? X0 : (z == 1) ? X1 : X2) : X0;
    const u16* Wt     = fused ? ((z == 0) ? W0 : (z == 1) ? W1 : W2) : W0;
    const float* bias = fused ? ((z == 0) ? b0 : (z == 1) ? b1 : b2) : b0;
    u16* OutB         = (z == 0) ? O0 : (z == 1) ? O1 : O2;
    const int mode    = fused ? ((z == 0) ? 1 : (z == 1) ? 3 : 2) : 0;

    const int srow = tid >> 3;            // p-chunk row 0..31
    const int scol = (tid & 7) * 8;

    frag_cd acc[2][4];
#pragma unroll
    for (int ms = 0; ms < 2; ++ms)
#pragma unroll
        for (int n = 0; n < 4; ++n) acc[ms][n] = (frag_cd){0.f, 0.f, 0.f, 0.f};

    for (int k0 = 0; k0 < Dd; k0 += 64) {
        __syncthreads();   // prev-iter LDS readers done
#pragma unroll
        for (int p = 0; p < 4; ++p)
            gload16(&X[(size_t)(m0 + p * 32 + srow) * Dd + k0 + scol],
                    &As[p * 2048 + wv * 512]);
#pragma unroll
        for (int p = 0; p < 2; ++p)
            gload16(&Wt[(size_t)(n0 + p * 32 + srow) * Dd + k0 + scol],
                    &Bs[p * 2048 + wv * 512]);
        __syncthreads();   // compiler drains vmcnt(0) here: staging complete

#pragma unroll
        for (int ks = 0; ks < 2; ++ks) {
            frag_ab a0 = *(const frag_ab*)&As[(wv * 32 + l16) * 64 + ks * 32 + quad * 8];
            frag_ab a1 = *(const frag_ab*)&As[(wv * 32 + 16 + l16) * 64 + ks * 32 + quad * 8];
#pragma unroll
            for (int n = 0; n < 4; ++n) {
                frag_ab b = *(const frag_ab*)&Bs[(n * 16 + l16) * 64 + ks * 32 + quad * 8];
                acc[0][n] = __builtin_amdgcn_mfma_f32_16x16x32_bf16(a0, b, acc[0][n], 0, 0, 0);
                acc[1][n] = __builtin_amdgcn_mfma_f32_16x16x32_bf16(a1, b, acc[1][n], 0, 0, 0);
            }
        }
    }

    float bv4[4];
#pragma unroll
    for (int n = 0; n < 4; ++n) bv4[n] = bias[n0 + n * 16 + l16];

    if (mode == 0) {
#pragma unroll
        for (int ms = 0; ms < 2; ++ms)
#pragma unroll
            for (int r = 0; r < 4; ++r) {
                int row = m0 + wv * 32 + ms * 16 + quad * 4 + r;
#pragma unroll
                for (int n = 0; n < 4; ++n)
                    OutF[(size_t)row * Dd + n0 + n * 16 + l16] = acc[ms][n][r] + bv4[n];
            }
    } else if (mode == 2) {
        const int h = n0 >> 6;
        const int b = m0 >> 11;
#pragma unroll
        for (int ms = 0; ms < 2; ++ms) {
            int sbase = (m0 & (Ss - 1)) + wv * 32 + ms * 16 + quad * 4;
#pragma unroll
            for (int n = 0; n < 4; ++n) {
                int d = n * 16 + l16;
                ushort4 o;
                o.x = f2bf(acc[ms][n][0] + bv4[n]);
                o.y = f2bf(acc[ms][n][1] + bv4[n]);
                o.z = f2bf(acc[ms][n][2] + bv4[n]);
                o.w = f2bf(acc[ms][n][3] + bv4[n]);
                *(ushort4*)&OutB[(((size_t)b * Hh + h) * DKk + d) * Ss + sbase] = o;
            }
        }
    } else {
        const int h = n0 >> 6;
        const float lg = 0.28782313662425575f;  // ln(10000)/32
        const float sc = (mode == 1) ? 0.125f : 1.0f;
#pragma unroll
        for (int ms = 0; ms < 2; ++ms)
#pragma unroll
            for (int r = 0; r < 4; ++r) {
                int row = m0 + wv * 32 + ms * 16 + quad * 4 + r;
                int b = row >> 11, s = row & (Ss - 1);
                u16* orow = OutB + (((size_t)b * Hh + h) * Ss + s) * DKk;
#pragma unroll
                for (int n = 0; n < 2; ++n) {
                    int j = n * 16 + l16;
                    float ang = (float)s * __expf(-(float)j * lg);
                    float cv = cosf(ang), sv = sinf(ang);
                    float lo = acc[ms][n][r] + bv4[n];
                    float hi = acc[ms][n + 2][r] + bv4[n + 2];
                    orow[j]      = f2bf((lo * cv - hi * sv) * sc);
                    orow[j + 32] = f2bf((hi * cv + lo * sv) * sc);
                }
            }
    }
}

// ---------------------------------------------------------------------------
// Out-projection GEMM — R7 version (neutral vs fused; kept: smaller footprint).
// ---------------------------------------------------------------------------
__global__ __launch_bounds__(256)
void gemm_out(const u16* __restrict__ X0, const u16* __restrict__ W0,
              const float* __restrict__ b0, float* __restrict__ OutF)
{
    __shared__ u16 As[64 * 64];
    __shared__ u16 Bs[64 * 64];

    const int tid = threadIdx.x;
    const int wv = tid >> 6, lane = tid & 63, l16 = lane & 15, quad = lane >> 4;
    const int n0 = blockIdx.x * 64, m0 = blockIdx.y * 64;

    const int srow = tid >> 3;            // p-chunk row 0..31
    const int scol = (tid & 7) * 8;

    frag_cd acc[4];
#pragma unroll
    for (int n = 0; n < 4; ++n) acc[n] = (frag_cd){0.f, 0.f, 0.f, 0.f};

    for (int k0 = 0; k0 < Dd; k0 += 64) {
        __syncthreads();   // prev-iter LDS readers done
#pragma unroll
        for (int p = 0; p < 2; ++p) {
            gload16(&X0[(size_t)(m0 + p * 32 + srow) * Dd + k0 + scol],
                    &As[p * 2048 + wv * 512]);
            gload16(&W0[(size_t)(n0 + p * 32 + srow) * Dd + k0 + scol],
                    &Bs[p * 2048 + wv * 512]);
        }
        __syncthreads();   // drains vmcnt(0): staging complete

#pragma unroll
        for (int ks = 0; ks < 2; ++ks) {
            frag_ab a0 = *(const frag_ab*)&As[(wv * 16 + l16) * 64 + ks * 32 + quad * 8];
#pragma unroll
            for (int n = 0; n < 4; ++n) {
                frag_ab b = *(const frag_ab*)&Bs[(n * 16 + l16) * 64 + ks * 32 + quad * 8];
                acc[n] = __builtin_amdgcn_mfma_f32_16x16x32_bf16(a0, b, acc[n], 0, 0, 0);
            }
        }
    }

    float bv4[4];
#pragma unroll
    for (int n = 0; n < 4; ++n) bv4[n] = b0[n0 + n * 16 + l16];

#pragma unroll
    for (int r = 0; r < 4; ++r) {
        int row = m0 + wv * 16 + quad * 4 + r;
#pragma unroll
        for (int n = 0; n < 4; ++n)
            OutF[(size_t)row * Dd + n0 + n * 16 + l16] = acc[n][r] + bv4[n];
    }
}

// ---------------------------------------------------------------------------
// MFMA flash attention — R10: SPLIT-K on the R9 frame (loop body unchanged).
// R9 evidence: occupancy avg 16.6% (concurrency decays 4->1 as short chains
// retire; grid == capacity so no backfill) while loads (R8) and softmax (R9)
// are both non-binding. Fix the SCHEDULE:
//  * q-tiles 0..15: one block, full chain (<=16 iters), direct output.
//  * q-tiles 16..31: TWO blocks — chunk A (kb 0..15, maskless) and chunk B
//    (kb 16..q, diag mask) — each writes unnormalized partials (of f32, m, l)
//    to workspace; attn_merge rescale-combines (exact flash-decoding math).
//  * max chain 32 -> 16; grid 1024 -> 1536 > 4/CU capacity => backfill.
//  * partials overlay qa/ka/va (dead after QKV gemm): of 16MiB, ml 512KiB.
// TRIPWIRES: Occupancy must RISE to ~28-35% (the mechanism); absmax
// 0.0078125 (merge bug => fail); attn+merge >= 73us combined => revert split.
// ---------------------------------------------------------------------------
__global__ __launch_bounds__(256)
void attn_mfma(const u16* __restrict__ Q, const u16* __restrict__ K,
               const u16* __restrict__ Vt, u16* __restrict__ Aout,
               float* __restrict__ ofP, float* __restrict__ mlP)
{
    __shared__ u16 Ks[2][64 * 64];
    __shared__ u16 Vs[2][64 * 64];
    __shared__ u16 Ps[64 * 64];

    const int tid = threadIdx.x;
    const int wv = tid >> 6;
    const int lane = tid & 63;
    const int l16 = lane & 15;
    const int quad = lane >> 4;

    const int bh = blockIdx.y;
    // rotate chain assignment per bh to scatter long chains across dispatch
    const int x = (blockIdx.x + bh * 5) % 48;
    int q, kb0, kb1, half;
    if (x < 32) { q = x; kb0 = 0; kb1 = (x < 16) ? x : 15; half = 0; }
    else        { q = x - 16; kb0 = 16; kb1 = q; half = 1; }
    const int split = (q >= 16);
    const int q0 = q * 64;

    const size_t qkbase = (size_t)bh * Ss * DKk;
    const size_t vbase  = (size_t)bh * DKk * Ss;
    const int b = bh >> 4, h = bh & 15;

    const int srow = tid >> 3;                       // 0..31
    const int scol = ((tid & 7) ^ (srow & 7)) * 8;   // swizzled global col (u16)
    const int sx   = (l16 & 7) * 8;                  // read-side XOR (u16)

    // Q fragments straight to registers
    frag_ab qreg[2];
    {
        const u16* qrow = &Q[qkbase + (size_t)(q0 + wv * 16 + l16) * DKk];
#pragma unroll
        for (int h2 = 0; h2 < 2; ++h2)
            qreg[h2] = *(const frag_ab*)&qrow[h2 * 32 + quad * 8];
    }

    // prologue: KV tile kb0 -> buffer 0
    {
        const int k0p = kb0 * 64;
#pragma unroll
        for (int p = 0; p < 2; ++p) {
            gload16(&K[qkbase + (size_t)(k0p + p * 32 + srow) * DKk + scol],
                    &Ks[0][p * 2048 + wv * 512]);
            gload16(&Vt[vbase + (size_t)(p * 32 + srow) * Ss + k0p + scol],
                    &Vs[0][p * 2048 + wv * 512]);
        }
    }

    float m_r = -3.0e38f, l_r = 0.f;     // per-lane: q = wv*16 + l16
    frag_cd of[4];
#pragma unroll
    for (int n = 0; n < 4; ++n) of[n] = (frag_cd){0.f, 0.f, 0.f, 0.f};

    const int nkb = kb1 - kb0 + 1;
    for (int i = 0; i < nkb; ++i) {
        const int kb = kb0 + i;
        const int cur = i & 1;
        const u16* KsB = Ks[cur];
        const u16* VsB = Vs[cur];

        __syncthreads();   // drains vmcnt(0): buf[cur] staged; orders prev readers

        if (i < nkb - 1) {
            const int k0n = (kb + 1) * 64;
#pragma unroll
            for (int p = 0; p < 2; ++p) {
                gload16(&K[qkbase + (size_t)(k0n + p * 32 + srow) * DKk + scol],
                        &Ks[cur ^ 1][p * 2048 + wv * 512]);
                gload16(&Vt[vbase + (size_t)(p * 32 + srow) * Ss + k0n + scol],
                        &Vs[cur ^ 1][p * 2048 + wv * 512]);
            }
        }

        // QK^T, SWAPPED: sf[n][r] = S[q = wv*16+l16][k = n*16+quad*4+r]
        frag_cd sf[4];
#pragma unroll
        for (int n = 0; n < 4; ++n) sf[n] = (frag_cd){0.f, 0.f, 0.f, 0.f};
#pragma unroll
        for (int h2 = 0; h2 < 2; ++h2) {
#pragma unroll
            for (int n = 0; n < 4; ++n) {
                frag_ab kf = *(const frag_ab*)&KsB[(n * 16 + l16) * 64 + ((h2 * 32 + quad * 8) ^ sx)];
                sf[n] = __builtin_amdgcn_mfma_f32_16x16x32_bf16(kf, qreg[h2], sf[n], 0, 0, 0);
            }
        }

        if (kb == q) {
            const int qloc = wv * 16 + l16;
#pragma unroll
            for (int n = 0; n < 4; ++n)
#pragma unroll
                for (int r = 0; r < 4; ++r)
                    if (n * 16 + quad * 4 + r > qloc) sf[n][r] = -1.0e30f;
        }

        // --- lane-local row softmax (R9) ---
        frag_cd t0, t1;
#pragma unroll
        for (int r = 0; r < 4; ++r) {
            t0[r] = fmaxf(sf[0][r], sf[1][r]);
            t1[r] = fmaxf(sf[2][r], sf[3][r]);
        }
        float mx = fmaxf(fmaxf(fmaxf(t0[0], t1[0]), fmaxf(t0[1], t1[1])),
                         fmaxf(fmaxf(t0[2], t1[2]), fmaxf(t0[3], t1[3])));
        mx = fmaxf(mx, m_r);
        mx = fmaxf(mx, __shfl_xor(mx, 16));
        mx = fmaxf(mx, __shfl_xor(mx, 32));

        float a = __expf(m_r - mx);
        m_r = mx;

        frag_cd s0, s1;
#pragma unroll
        for (int n = 0; n < 4; ++n)
#pragma unroll
            for (int r = 0; r < 4; ++r)
                sf[n][r] = __expf(sf[n][r] - mx);
#pragma unroll
        for (int r = 0; r < 4; ++r) {
            s0[r] = sf[0][r] + sf[1][r];
            s1[r] = sf[2][r] + sf[3][r];
        }
        float sum = ((s0[0] + s1[0]) + (s0[1] + s1[1])) +
                    ((s0[2] + s1[2]) + (s0[3] + s1[3]));
        sum += __shfl_xor(sum, 16);
        sum += __shfl_xor(sum, 32);
        l_r = l_r * a + sum;

        float a4[4];
#pragma unroll
        for (int r = 0; r < 4; ++r)
            a4[r] = __shfl(a, (lane & 48) | (quad * 4 + r));
#pragma unroll
        for (int n = 0; n < 4; ++n)
#pragma unroll
            for (int r = 0; r < 4; ++r) of[n][r] *= a4[r];

        // P -> LDS: 4x ushort4 into the swizzled [64][64]
        {
            const int prow = wv * 16 + l16;
            const int px8  = (l16 & 7) << 3;
#pragma unroll
            for (int n = 0; n < 4; ++n) {
                ushort4 o;
                o.x = f2bf(sf[n][0]); o.y = f2bf(sf[n][1]);
                o.z = f2bf(sf[n][2]); o.w = f2bf(sf[n][3]);
                *(ushort4*)&Ps[prow * 64 + ((n * 16 + quad * 4) ^ px8)] = o;
            }
        }
        __threadfence_block();   // wave-private P strip: intra-wave order only

#pragma unroll
        for (int h2 = 0; h2 < 2; ++h2) {
            frag_ab pa = *(const frag_ab*)&Ps[(wv * 16 + l16) * 64 + ((h2 * 32 + quad * 8) ^ sx)];
#pragma unroll
            for (int n = 0; n < 4; ++n) {
                frag_ab vf = *(const frag_ab*)&VsB[(n * 16 + l16) * 64 + ((h2 * 32 + quad * 8) ^ sx)];
                of[n] = __builtin_amdgcn_mfma_f32_16x16x32_bf16(pa, vf, of[n], 0, 0, 0);
            }
        }
    }

    if (!split) {
        // direct output: 1/l at lane l16=q; broadcast to C-layout rows
        float linv = 1.f / l_r;
        float inv4[4];
#pragma unroll
        for (int r = 0; r < 4; ++r)
            inv4[r] = __shfl(linv, (lane & 48) | (quad * 4 + r));
#pragma unroll
        for (int r = 0; r < 4; ++r) {
            int row = q0 + wv * 16 + quad * 4 + r;
            u16* orow = Aout + ((size_t)b * Ss + row) * Dd + h * DKk;
#pragma unroll
            for (int n = 0; n < 4; ++n) orow[n * 16 + l16] = f2bf(of[n][r] * inv4[r]);
        }
    } else {
        // partials: of (unnormalized, f32) + m/l per q-row
        const size_t pbase = (((size_t)bh * 16 + (q - 16)) * 2 + half) * 4096;
#pragma unroll
        for (int r = 0; r < 4; ++r) {
            int row = wv * 16 + quad * 4 + r;
#pragma unroll
            for (int n = 0; n < 4; ++n)
                ofP[pbase + (size_t)row * 64 + n * 16 + l16] = of[n][r];
        }
        if (quad == 0) {
            const size_t mb = (((size_t)bh * 16 + (q - 16)) * 2 + half) * 128;
            mlP[mb + wv * 16 + l16]      = m_r;
            mlP[mb + 64 + wv * 16 + l16] = l_r;
        }
    }
}

// ---------------------------------------------------------------------------
// Flash-decoding merge: combine the two partial halves of split q-tiles.
// out = (ofA*expf(mA-m) + ofB*expf(mB-m)) / (lA*expf(mA-m) + lB*expf(mB-m))
// ---------------------------------------------------------------------------
__global__ __launch_bounds__(256)
void attn_merge(const float* __restrict__ ofP, const float* __restrict__ mlP,
                u16* __restrict__ Aout)
{
    const int s = blockIdx.x;    // 0..15 -> q-tile s+16
    const int bh = blockIdx.y;   // 0..31
    const int tid = threadIdx.x;
    const int row = tid >> 2;          // 0..63
    const int c0  = (tid & 3) * 16;    // 16 cols per thread
    const int b = bh >> 4, h = bh & 15;
    const int q0 = (s + 16) * 64;

    const size_t baseA = (((size_t)bh * 16 + s) * 2 + 0) * 4096 + (size_t)row * 64;
    const size_t baseB = baseA + 4096;
    const size_t mbA = (((size_t)bh * 16 + s) * 2 + 0) * 128;
    const size_t mbB = mbA + 128;

    float mA = mlP[mbA + row], lA = mlP[mbA + 64 + row];
    float mB = mlP[mbB + row], lB = mlP[mbB + 64 + row];
    float m  = fmaxf(mA, mB);
    float aA = __expf(mA - m), aB = __expf(mB - m);
    float inv = 1.f / (lA * aA + lB * aB);

    u16* orow = Aout + ((size_t)b * Ss + q0 + row) * Dd + h * DKk;
#pragma unroll
    for (int j4 = 0; j4 < 4; ++j4) {
        float4 vA = *(const float4*)&ofP[baseA + c0 + j4 * 4];
        float4 vB = *(const float4*)&ofP[baseB + c0 + j4 * 4];
        ushort4 o;
        o.x = f2bf((vA.x * aA + vB.x * aB) * inv);
        o.y = f2bf((vA.y * aA + vB.y * aB) * inv);
        o.z = f2bf((vA.z * aA + vB.z * aB) * inv);
        o.w = f2bf((vA.w * aA + vB.w * aB) * inv);
        *(ushort4*)&orow[c0 + j4 * 4] = o;
    }
}

extern "C" void kernel_launch(void* const* d_in, const int* in_sizes, int n_in,
                              void* d_out, int out_size, void* d_ws, size_t ws_size,
                              hipStream_t stream) {
    (void)in_sizes; (void)n_in; (void)out_size;
    const float* q  = (const float*)d_in[0];
    const float* k  = (const float*)d_in[1];
    const float* v  = (const float*)d_in[2];
    // d_in[3] = mask (tril causal) -- enforced analytically in attn_mfma
    const float* Wq = (const float*)d_in[4];
    const float* bq = (const float*)d_in[5];
    const float* Wk = (const float*)d_in[6];
    const float* bk = (const float*)d_in[7];
    const float* Wv = (const float*)d_in[8];
    const float* bv = (const float*)d_in[9];
    const float* Wo = (const float*)d_in[10];
    const float* bo = (const float*)d_in[11];
    float* out = (float*)d_out;

    const size_t E = (size_t)Bb * Ss * Dd;     // 4,194,304
    const size_t Wn = (size_t)Dd * Dd;         // 1,048,576
    const size_t need = (7 * E + 4 * Wn) * sizeof(u16);   // 64 MiB
    if (ws_size < need) return;
    u16* qa  = (u16*)d_ws;
    u16* ka  = qa + E;
    u16* va  = ka + E;
    u16* wqt = va + E;
    u16* wkt = wqt + Wn;
    u16* wvt = wkt + Wn;
    u16* wot = wvt + Wn;
    u16* Qh  = wot + Wn;
    u16* Kh  = Qh + E;
    u16* Vth = Kh + E;
    u16* Abf = Vth + E;

    // split-K partials overlay qa..ka (16 MiB) and va (512 KiB) — both dead
    // after the QKV gemm completes (stream-ordered).
    float* ofP = (float*)qa;
    float* mlP = (float*)va;

    convert_kernel<<<4096, 256, 0, stream>>>(q, k, v, Wq, Wk, Wv, Wo,
                                             qa, ka, va, wqt, wkt, wvt, wot);
    gemm_bf16<<<dim3(Dd / 64, BSn / 128, 3), 256, 0, stream>>>(
        qa, ka, va, wqt, wkt, wvt, bq, bk, bv, Qh, Kh, Vth, nullptr, 1);
    attn_mfma<<<dim3(48, Bb * Hh), 256, 0, stream>>>(Qh, Kh, Vth, Abf, ofP, mlP);
    attn_merge<<<dim3(16, Bb * Hh), 256, 0, stream>>>(ofP, mlP, Abf);
    gemm_out<<<dim3(Dd / 64, BSn / 64), 256, 0, stream>>>(Abf, wot, bo, out);
}

// Round 11
// 262.103 us; speedup vs baseline: 1.0682x; 1.0011x over previous
//
#include <hip/hip_runtime.h>
#include <hip/hip_bf16.h>
#include <math.h>

#define Bb 2
#define Ss 2048
#define Dd 1024
#define Hh 16
#define DKk 64
#define BSn (Bb*Ss)

typedef unsigned short u16;
typedef __attribute__((ext_vector_type(8))) short frag_ab;   // 8 bf16
typedef __attribute__((ext_vector_type(4))) float frag_cd;   // 4 f32

static __device__ __forceinline__ u16 f2bf(float x) {
    __hip_bfloat16 h = __float2bfloat16(x);
    return *reinterpret_cast<u16*>(&h);
}

// Direct global->LDS async copy, 16B per lane. LDS dest is the wave-uniform
// base; HW writes lane i at base + i*16B. Requires LINEAR (unpadded) LDS.
static __device__ __forceinline__ void gload16(const u16* g, u16* l) {
    __builtin_amdgcn_global_load_lds(
        (const __attribute__((address_space(1))) void*)g,
        (__attribute__((address_space(3))) void*)l, 16, 0, 0);
}

// ---------------------------------------------------------------------------
// One-shot convert: q,k,v fp32 -> bf16; W* fp32 [k][n] -> bf16 transposed [n][k].
// ---------------------------------------------------------------------------
__global__ __launch_bounds__(256)
void convert_kernel(const float* __restrict__ q, const float* __restrict__ k,
                    const float* __restrict__ v,
                    const float* __restrict__ Wq, const float* __restrict__ Wk,
                    const float* __restrict__ Wv, const float* __restrict__ Wo,
                    u16* __restrict__ qb, u16* __restrict__ kb, u16* __restrict__ vb,
                    u16* __restrict__ wqt, u16* __restrict__ wkt,
                    u16* __restrict__ wvt, u16* __restrict__ wot)
{
    __shared__ u16 T[64 * 80];
    const int tid = threadIdx.x;
    const int bid = blockIdx.x;
    if (bid < 3072) {
        int t = bid >> 10;
        const float* src = (t == 0) ? q : (t == 1) ? k : v;
        u16* dst = (t == 0) ? qb : (t == 1) ? kb : vb;
        size_t base = (size_t)(bid & 1023) * 4096;
#pragma unroll
        for (int i = 0; i < 4; ++i) {
            size_t e = base + (size_t)(tid + i * 256) * 4;
            float4 xv = *(const float4*)(src + e);
            ushort4 o;
            o.x = f2bf(xv.x); o.y = f2bf(xv.y); o.z = f2bf(xv.z); o.w = f2bf(xv.w);
            *(ushort4*)(dst + e) = o;
        }
    } else {
        int wbid = bid - 3072;
        int w = wbid >> 8;
        const float* src = (w == 0) ? Wq : (w == 1) ? Wk : (w == 2) ? Wv : Wo;
        u16* dst = (w == 0) ? wqt : (w == 1) ? wkt : (w == 2) ? wvt : wot;
        int t = wbid & 255;
        int k0 = (t >> 4) * 64, nt0 = (t & 15) * 64;
#pragma unroll
        for (int i = 0; i < 4; ++i) {
            int f = tid + i * 256;
            int kk = f >> 4, nn = (f & 15) * 4;
            float4 xv = *(const float4*)(src + (size_t)(k0 + kk) * Dd + nt0 + nn);
            T[(nn + 0) * 80 + kk] = f2bf(xv.x);
            T[(nn + 1) * 80 + kk] = f2bf(xv.y);
            T[(nn + 2) * 80 + kk] = f2bf(xv.z);
            T[(nn + 3) * 80 + kk] = f2bf(xv.w);
        }
        __syncthreads();
#pragma unroll
        for (int i = 0; i < 2; ++i) {
            int g = tid + i * 256;
            int nn = g >> 3, k8 = (g & 7) * 8;
            *(uint4*)(dst + (size_t)(nt0 + nn) * Dd + k0 + k8) =
                *(const uint4*)&T[nn * 80 + k8];
        }
    }
}

// ---------------------------------------------------------------------------
// bf16 MFMA GEMM — R4 frame + R11 change: rule-21 XOR swizzle on staging and
// reads (the R5/R6-proven involution from attn). R10 PMC showed 1.4e7 bank
// conflicts/dispatch = ~27% of wall cycles on the barrier->ds_read->MFMA
// critical path (linear [R][64] tile = 16-way conflict). Source col
// pre-swizzled by row&7; reads XOR col with (l16&7)*8 — every read row has
// row&7 == l16&7 (a0: wv*32+l16; a1: +16; b: n*16+l16).
// R1 post-mortem still governs: do NOT grow acc/fragment count.
// TRIPWIRES: conflicts -> <2M; absmax 0.0078125; VGPR ~52.
// ---------------------------------------------------------------------------
__global__ __launch_bounds__(256)
void gemm_bf16(const u16* __restrict__ X0, const u16* __restrict__ X1,
               const u16* __restrict__ X2,
               const u16* __restrict__ W0, const u16* __restrict__ W1,
               const u16* __restrict__ W2,
               const float* __restrict__ b0, const float* __restrict__ b1,
               const float* __restrict__ b2,
               u16* __restrict__ O0, u16* __restrict__ O1, u16* __restrict__ O2,
               float* __restrict__ OutF, int fused)
{
    __shared__ u16 As[128 * 64];
    __shared__ u16 Bs[64 * 64];

    const int tid = threadIdx.x;
    const int wv = tid >> 6, lane = tid & 63, l16 = lane & 15, quad = lane >> 4;
    const int n0 = blockIdx.x * 64, m0 = blockIdx.y * 128;
    const int z = blockIdx.z;

    const u16* X      = fused ? ((z == 0) ? X0 : (z == 1) ? X1 : X2) : X0;
    const u16* Wt     = fused ? ((z == 0) ? W0 : (z == 1) ? W1 : W2) : W0;
    const float* bias = fused ? ((z == 0) ? b0 : (z == 1) ? b1 : b2) : b0;
    u16* OutB         = (z == 0) ? O0 : (z == 1) ? O1 : O2;
    const int mode    = fused ? ((z == 0) ? 1 : (z == 1) ? 3 : 2) : 0;

    const int srow = tid >> 3;                       // p-chunk row 0..31
    const int scol = ((tid & 7) ^ (srow & 7)) * 8;   // swizzled global col (u16)
    const int sx   = (l16 & 7) * 8;                  // read-side XOR (u16)

    frag_cd acc[2][4];
#pragma unroll
    for (int ms = 0; ms < 2; ++ms)
#pragma unroll
        for (int n = 0; n < 4; ++n) acc[ms][n] = (frag_cd){0.f, 0.f, 0.f, 0.f};

    for (int k0 = 0; k0 < Dd; k0 += 64) {
        __syncthreads();   // prev-iter LDS readers done
#pragma unroll
        for (int p = 0; p < 4; ++p)
            gload16(&X[(size_t)(m0 + p * 32 + srow) * Dd + k0 + scol],
                    &As[p * 2048 + wv * 512]);
#pragma unroll
        for (int p = 0; p < 2; ++p)
            gload16(&Wt[(size_t)(n0 + p * 32 + srow) * Dd + k0 + scol],
                    &Bs[p * 2048 + wv * 512]);
        __syncthreads();   // compiler drains vmcnt(0) here: staging complete

#pragma unroll
        for (int ks = 0; ks < 2; ++ks) {
            frag_ab a0 = *(const frag_ab*)&As[(wv * 32 + l16) * 64 + ((ks * 32 + quad * 8) ^ sx)];
            frag_ab a1 = *(const frag_ab*)&As[(wv * 32 + 16 + l16) * 64 + ((ks * 32 + quad * 8) ^ sx)];
#pragma unroll
            for (int n = 0; n < 4; ++n) {
                frag_ab b = *(const frag_ab*)&Bs[(n * 16 + l16) * 64 + ((ks * 32 + quad * 8) ^ sx)];
                acc[0][n] = __builtin_amdgcn_mfma_f32_16x16x32_bf16(a0, b, acc[0][n], 0, 0, 0);
                acc[1][n] = __builtin_amdgcn_mfma_f32_16x16x32_bf16(a1, b, acc[1][n], 0, 0, 0);
            }
        }
    }

    float bv4[4];
#pragma unroll
    for (int n = 0; n < 4; ++n) bv4[n] = bias[n0 + n * 16 + l16];

    if (mode == 0) {
#pragma unroll
        for (int ms = 0; ms < 2; ++ms)
#pragma unroll
            for (int r = 0; r < 4; ++r) {
                int row = m0 + wv * 32 + ms * 16 + quad * 4 + r;
#pragma unroll
                for (int n = 0; n < 4; ++n)
                    OutF[(size_t)row * Dd + n0 + n * 16 + l16] = acc[ms][n][r] + bv4[n];
            }
    } else if (mode == 2) {
        const int h = n0 >> 6;
        const int b = m0 >> 11;
#pragma unroll
        for (int ms = 0; ms < 2; ++ms) {
            int sbase = (m0 & (Ss - 1)) + wv * 32 + ms * 16 + quad * 4;
#pragma unroll
            for (int n = 0; n < 4; ++n) {
                int d = n * 16 + l16;
                ushort4 o;
                o.x = f2bf(acc[ms][n][0] + bv4[n]);
                o.y = f2bf(acc[ms][n][1] + bv4[n]);
                o.z = f2bf(acc[ms][n][2] + bv4[n]);
                o.w = f2bf(acc[ms][n][3] + bv4[n]);
                *(ushort4*)&OutB[(((size_t)b * Hh + h) * DKk + d) * Ss + sbase] = o;
            }
        }
    } else {
        const int h = n0 >> 6;
        const float lg = 0.28782313662425575f;  // ln(10000)/32
        const float sc = (mode == 1) ? 0.125f : 1.0f;
#pragma unroll
        for (int ms = 0; ms < 2; ++ms)
#pragma unroll
            for (int r = 0; r < 4; ++r) {
                int row = m0 + wv * 32 + ms * 16 + quad * 4 + r;
                int b = row >> 11, s = row & (Ss - 1);
                u16* orow = OutB + (((size_t)b * Hh + h) * Ss + s) * DKk;
#pragma unroll
                for (int n = 0; n < 2; ++n) {
                    int j = n * 16 + l16;
                    float ang = (float)s * __expf(-(float)j * lg);
                    float cv = cosf(ang), sv = sinf(ang);
                    float lo = acc[ms][n][r] + bv4[n];
                    float hi = acc[ms][n + 2][r] + bv4[n + 2];
                    orow[j]      = f2bf((lo * cv - hi * sv) * sc);
                    orow[j + 32] = f2bf((hi * cv + lo * sv) * sc);
                }
            }
    }
}

// ---------------------------------------------------------------------------
// Out-projection GEMM — R7 frame + R11 swizzle (same involution; read rows
// wv*16+l16 and n*16+l16 both have row&7 == l16&7).
// ---------------------------------------------------------------------------
__global__ __launch_bounds__(256)
void gemm_out(const u16* __restrict__ X0, const u16* __restrict__ W0,
              const float* __restrict__ b0, float* __restrict__ OutF)
{
    __shared__ u16 As[64 * 64];
    __shared__ u16 Bs[64 * 64];

    const int tid = threadIdx.x;
    const int wv = tid >> 6, lane = tid & 63, l16 = lane & 15, quad = lane >> 4;
    const int n0 = blockIdx.x * 64, m0 = blockIdx.y * 64;

    const int srow = tid >> 3;                       // p-chunk row 0..31
    const int scol = ((tid & 7) ^ (srow & 7)) * 8;   // swizzled global col (u16)
    const int sx   = (l16 & 7) * 8;                  // read-side XOR (u16)

    frag_cd acc[4];
#pragma unroll
    for (int n = 0; n < 4; ++n) acc[n] = (frag_cd){0.f, 0.f, 0.f, 0.f};

    for (int k0 = 0; k0 < Dd; k0 += 64) {
        __syncthreads();   // prev-iter LDS readers done
#pragma unroll
        for (int p = 0; p < 2; ++p) {
            gload16(&X0[(size_t)(m0 + p * 32 + srow) * Dd + k0 + scol],
                    &As[p * 2048 + wv * 512]);
            gload16(&W0[(size_t)(n0 + p * 32 + srow) * Dd + k0 + scol],
                    &Bs[p * 2048 + wv * 512]);
        }
        __syncthreads();   // drains vmcnt(0): staging complete

#pragma unroll
        for (int ks = 0; ks < 2; ++ks) {
            frag_ab a0 = *(const frag_ab*)&As[(wv * 16 + l16) * 64 + ((ks * 32 + quad * 8) ^ sx)];
#pragma unroll
            for (int n = 0; n < 4; ++n) {
                frag_ab b = *(const frag_ab*)&Bs[(n * 16 + l16) * 64 + ((ks * 32 + quad * 8) ^ sx)];
                acc[n] = __builtin_amdgcn_mfma_f32_16x16x32_bf16(a0, b, acc[n], 0, 0, 0);
            }
        }
    }

    float bv4[4];
#pragma unroll
    for (int n = 0; n < 4; ++n) bv4[n] = b0[n0 + n * 16 + l16];

#pragma unroll
    for (int r = 0; r < 4; ++r) {
        int row = m0 + wv * 16 + quad * 4 + r;
#pragma unroll
        for (int n = 0; n < 4; ++n)
            OutF[(size_t)row * Dd + n0 + n * 16 + l16] = acc[n][r] + bv4[n];
    }
}

// ---------------------------------------------------------------------------
// MFMA flash attention — R10 split-K version VERBATIM (WIN: attn left top-5,
// <85us; occupancy backfill via max-chain 16 + grid 1536).
// ---------------------------------------------------------------------------
__global__ __launch_bounds__(256)
void attn_mfma(const u16* __restrict__ Q, const u16* __restrict__ K,
               const u16* __restrict__ Vt, u16* __restrict__ Aout,
               float* __restrict__ ofP, float* __restrict__ mlP)
{
    __shared__ u16 Ks[2][64 * 64];
    __shared__ u16 Vs[2][64 * 64];
    __shared__ u16 Ps[64 * 64];

    const int tid = threadIdx.x;
    const int wv = tid >> 6;
    const int lane = tid & 63;
    const int l16 = lane & 15;
    const int quad = lane >> 4;

    const int bh = blockIdx.y;
    // rotate chain assignment per bh to scatter long chains across dispatch
    const int x = (blockIdx.x + bh * 5) % 48;
    int q, kb0, kb1, half;
    if (x < 32) { q = x; kb0 = 0; kb1 = (x < 16) ? x : 15; half = 0; }
    else        { q = x - 16; kb0 = 16; kb1 = q; half = 1; }
    const int split = (q >= 16);
    const int q0 = q * 64;

    const size_t qkbase = (size_t)bh * Ss * DKk;
    const size_t vbase  = (size_t)bh * DKk * Ss;
    const int b = bh >> 4, h = bh & 15;

    const int srow = tid >> 3;                       // 0..31
    const int scol = ((tid & 7) ^ (srow & 7)) * 8;   // swizzled global col (u16)
    const int sx   = (l16 & 7) * 8;                  // read-side XOR (u16)

    // Q fragments straight to registers
    frag_ab qreg[2];
    {
        const u16* qrow = &Q[qkbase + (size_t)(q0 + wv * 16 + l16) * DKk];
#pragma unroll
        for (int h2 = 0; h2 < 2; ++h2)
            qreg[h2] = *(const frag_ab*)&qrow[h2 * 32 + quad * 8];
    }

    // prologue: KV tile kb0 -> buffer 0
    {
        const int k0p = kb0 * 64;
#pragma unroll
        for (int p = 0; p < 2; ++p) {
            gload16(&K[qkbase + (size_t)(k0p + p * 32 + srow) * DKk + scol],
                    &Ks[0][p * 2048 + wv * 512]);
            gload16(&Vt[vbase + (size_t)(p * 32 + srow) * Ss + k0p + scol],
                    &Vs[0][p * 2048 + wv * 512]);
        }
    }

    float m_r = -3.0e38f, l_r = 0.f;     // per-lane: q = wv*16 + l16
    frag_cd of[4];
#pragma unroll
    for (int n = 0; n < 4; ++n) of[n] = (frag_cd){0.f, 0.f, 0.f, 0.f};

    const int nkb = kb1 - kb0 + 1;
    for (int i = 0; i < nkb; ++i) {
        const int kb = kb0 + i;
        const int cur = i & 1;
        const u16* KsB = Ks[cur];
        const u16* VsB = Vs[cur];

        __syncthreads();   // drains vmcnt(0): buf[cur] staged; orders prev readers

        if (i < nkb - 1) {
            const int k0n = (kb + 1) * 64;
#pragma unroll
            for (int p = 0; p < 2; ++p) {
                gload16(&K[qkbase + (size_t)(k0n + p * 32 + srow) * DKk + scol],
                        &Ks[cur ^ 1][p * 2048 + wv * 512]);
                gload16(&Vt[vbase + (size_t)(p * 32 + srow) * Ss + k0n + scol],
                        &Vs[cur ^ 1][p * 2048 + wv * 512]);
            }
        }

        // QK^T, SWAPPED: sf[n][r] = S[q = wv*16+l16][k = n*16+quad*4+r]
        frag_cd sf[4];
#pragma unroll
        for (int n = 0; n < 4; ++n) sf[n] = (frag_cd){0.f, 0.f, 0.f, 0.f};
#pragma unroll
        for (int h2 = 0; h2 < 2; ++h2) {
#pragma unroll
            for (int n = 0; n < 4; ++n) {
                frag_ab kf = *(const frag_ab*)&KsB[(n * 16 + l16) * 64 + ((h2 * 32 + quad * 8) ^ sx)];
                sf[n] = __builtin_amdgcn_mfma_f32_16x16x32_bf16(kf, qreg[h2], sf[n], 0, 0, 0);
            }
        }

        if (kb == q) {
            const int qloc = wv * 16 + l16;
#pragma unroll
            for (int n = 0; n < 4; ++n)
#pragma unroll
                for (int r = 0; r < 4; ++r)
                    if (n * 16 + quad * 4 + r > qloc) sf[n][r] = -1.0e30f;
        }

        // --- lane-local row softmax (R9) ---
        frag_cd t0, t1;
#pragma unroll
        for (int r = 0; r < 4; ++r) {
            t0[r] = fmaxf(sf[0][r], sf[1][r]);
            t1[r] = fmaxf(sf[2][r], sf[3][r]);
        }
        float mx = fmaxf(fmaxf(fmaxf(t0[0], t1[0]), fmaxf(t0[1], t1[1])),
                         fmaxf(fmaxf(t0[2], t1[2]), fmaxf(t0[3], t1[3])));
        mx = fmaxf(mx, m_r);
        mx = fmaxf(mx, __shfl_xor(mx, 16));
        mx = fmaxf(mx, __shfl_xor(mx, 32));

        float a = __expf(m_r - mx);
        m_r = mx;

        frag_cd s0, s1;
#pragma unroll
        for (int n = 0; n < 4; ++n)
#pragma unroll
            for (int r = 0; r < 4; ++r)
                sf[n][r] = __expf(sf[n][r] - mx);
#pragma unroll
        for (int r = 0; r < 4; ++r) {
            s0[r] = sf[0][r] + sf[1][r];
            s1[r] = sf[2][r] + sf[3][r];
        }
        float sum = ((s0[0] + s1[0]) + (s0[1] + s1[1])) +
                    ((s0[2] + s1[2]) + (s0[3] + s1[3]));
        sum += __shfl_xor(sum, 16);
        sum += __shfl_xor(sum, 32);
        l_r = l_r * a + sum;

        float a4[4];
#pragma unroll
        for (int r = 0; r < 4; ++r)
            a4[r] = __shfl(a, (lane & 48) | (quad * 4 + r));
#pragma unroll
        for (int n = 0; n < 4; ++n)
#pragma unroll
            for (int r = 0; r < 4; ++r) of[n][r] *= a4[r];

        // P -> LDS: 4x ushort4 into the swizzled [64][64]
        {
            const int prow = wv * 16 + l16;
            const int px8  = (l16 & 7) << 3;
#pragma unroll
            for (int n = 0; n < 4; ++n) {
                ushort4 o;
                o.x = f2bf(sf[n][0]); o.y = f2bf(sf[n][1]);
                o.z = f2bf(sf[n][2]); o.w = f2bf(sf[n][3]);
                *(ushort4*)&Ps[prow * 64 + ((n * 16 + quad * 4) ^ px8)] = o;
            }
        }
        __threadfence_block();   // wave-private P strip: intra-wave order only

#pragma unroll
        for (int h2 = 0; h2 < 2; ++h2) {
            frag_ab pa = *(const frag_ab*)&Ps[(wv * 16 + l16) * 64 + ((h2 * 32 + quad * 8) ^ sx)];
#pragma unroll
            for (int n = 0; n < 4; ++n) {
                frag_ab vf = *(const frag_ab*)&VsB[(n * 16 + l16) * 64 + ((h2 * 32 + quad * 8) ^ sx)];
                of[n] = __builtin_amdgcn_mfma_f32_16x16x32_bf16(pa, vf, of[n], 0, 0, 0);
            }
        }
    }

    if (!split) {
        // direct output: 1/l at lane l16=q; broadcast to C-layout rows
        float linv = 1.f / l_r;
        float inv4[4];
#pragma unroll
        for (int r = 0; r < 4; ++r)
            inv4[r] = __shfl(linv, (lane & 48) | (quad * 4 + r));
#pragma unroll
        for (int r = 0; r < 4; ++r) {
            int row = q0 + wv * 16 + quad * 4 + r;
            u16* orow = Aout + ((size_t)b * Ss + row) * Dd + h * DKk;
#pragma unroll
            for (int n = 0; n < 4; ++n) orow[n * 16 + l16] = f2bf(of[n][r] * inv4[r]);
        }
    } else {
        // partials: of (unnormalized, f32) + m/l per q-row
        const size_t pbase = (((size_t)bh * 16 + (q - 16)) * 2 + half) * 4096;
#pragma unroll
        for (int r = 0; r < 4; ++r) {
            int row = wv * 16 + quad * 4 + r;
#pragma unroll
            for (int n = 0; n < 4; ++n)
                ofP[pbase + (size_t)row * 64 + n * 16 + l16] = of[n][r];
        }
        if (quad == 0) {
            const size_t mb = (((size_t)bh * 16 + (q - 16)) * 2 + half) * 128;
            mlP[mb + wv * 16 + l16]      = m_r;
            mlP[mb + 64 + wv * 16 + l16] = l_r;
        }
    }
}

// ---------------------------------------------------------------------------
// Flash-decoding merge: combine the two partial halves of split q-tiles.
// ---------------------------------------------------------------------------
__global__ __launch_bounds__(256)
void attn_merge(const float* __restrict__ ofP, const float* __restrict__ mlP,
                u16* __restrict__ Aout)
{
    const int s = blockIdx.x;    // 0..15 -> q-tile s+16
    const int bh = blockIdx.y;   // 0..31
    const int tid = threadIdx.x;
    const int row = tid >> 2;          // 0..63
    const int c0  = (tid & 3) * 16;    // 16 cols per thread
    const int b = bh >> 4, h = bh & 15;
    const int q0 = (s + 16) * 64;

    const size_t baseA = (((size_t)bh * 16 + s) * 2 + 0) * 4096 + (size_t)row * 64;
    const size_t baseB = baseA + 4096;
    const size_t mbA = (((size_t)bh * 16 + s) * 2 + 0) * 128;
    const size_t mbB = mbA + 128;

    float mA = mlP[mbA + row], lA = mlP[mbA + 64 + row];
    float mB = mlP[mbB + row], lB = mlP[mbB + 64 + row];
    float m  = fmaxf(mA, mB);
    float aA = __expf(mA - m), aB = __expf(mB - m);
    float inv = 1.f / (lA * aA + lB * aB);

    u16* orow = Aout + ((size_t)b * Ss + q0 + row) * Dd + h * DKk;
#pragma unroll
    for (int j4 = 0; j4 < 4; ++j4) {
        float4 vA = *(const float4*)&ofP[baseA + c0 + j4 * 4];
        float4 vB = *(const float4*)&ofP[baseB + c0 + j4 * 4];
        ushort4 o;
        o.x = f2bf((vA.x * aA + vB.x * aB) * inv);
        o.y = f2bf((vA.y * aA + vB.y * aB) * inv);
        o.z = f2bf((vA.z * aA + vB.z * aB) * inv);
        o.w = f2bf((vA.w * aA + vB.w * aB) * inv);
        *(ushort4*)&orow[c0 + j4 * 4] = o;
    }
}

extern "C" void kernel_launch(void* const* d_in, const int* in_sizes, int n_in,
                              void* d_out, int out_size, void* d_ws, size_t ws_size,
                              hipStream_t stream) {
    (void)in_sizes; (void)n_in; (void)out_size;
    const float* q  = (const float*)d_in[0];
    const float* k  = (const float*)d_in[1];
    const float* v  = (const float*)d_in[2];
    // d_in[3] = mask (tril causal) -- enforced analytically in attn_mfma
    const float* Wq = (const float*)d_in[4];
    const float* bq = (const float*)d_in[5];
    const float* Wk = (const float*)d_in[6];
    const float* bk = (const float*)d_in[7];
    const float* Wv = (const float*)d_in[8];
    const float* bv = (const float*)d_in[9];
    const float* Wo = (const float*)d_in[10];
    const float* bo = (const float*)d_in[11];
    float* out = (float*)d_out;

    const size_t E = (size_t)Bb * Ss * Dd;     // 4,194,304
    const size_t Wn = (size_t)Dd * Dd;         // 1,048,576
    const size_t need = (7 * E + 4 * Wn) * sizeof(u16);   // 64 MiB
    if (ws_size < need) return;
    u16* qa  = (u16*)d_ws;
    u16* ka  = qa + E;
    u16* va  = ka + E;
    u16* wqt = va + E;
    u16* wkt = wqt + Wn;
    u16* wvt = wkt + Wn;
    u16* wot = wvt + Wn;
    u16* Qh  = wot + Wn;
    u16* Kh  = Qh + E;
    u16* Vth = Kh + E;
    u16* Abf = Vth + E;

    // split-K partials overlay qa..ka (16 MiB) and va (512 KiB) — both dead
    // after the QKV gemm completes (stream-ordered).
    float* ofP = (float*)qa;
    float* mlP = (float*)va;

    convert_kernel<<<4096, 256, 0, stream>>>(q, k, v, Wq, Wk, Wv, Wo,
                                             qa, ka, va, wqt, wkt, wvt, wot);
    gemm_bf16<<<dim3(Dd / 64, BSn / 128, 3), 256, 0, stream>>>(
        qa, ka, va, wqt, wkt, wvt, bq, bk, bv, Qh, Kh, Vth, nullptr, 1);
    attn_mfma<<<dim3(48, Bb * Hh), 256, 0, stream>>>(Qh, Kh, Vth, Abf, ofP, mlP);
    attn_merge<<<dim3(16, Bb * Hh), 256, 0, stream>>>(ofP, mlP, Abf);
    gemm_out<<<dim3(Dd / 64, BSn / 64), 256, 0, stream>>>(Abf, wot, bo, out);
}

// Round 12
// 261.839 us; speedup vs baseline: 1.0693x; 1.0010x over previous
//
#include <hip/hip_runtime.h>
#include <hip/hip_bf16.h>
#include <math.h>

#define Bb 2
#define Ss 2048
#define Dd 1024
#define Hh 16
#define DKk 64
#define BSn (Bb*Ss)

typedef unsigned short u16;
typedef __attribute__((ext_vector_type(8))) short frag_ab;   // 8 bf16
typedef __attribute__((ext_vector_type(4))) float frag_cd;   // 4 f32

static __device__ __forceinline__ u16 f2bf(float x) {
    __hip_bfloat16 h = __float2bfloat16(x);
    return *reinterpret_cast<u16*>(&h);
}

// Direct global->LDS async copy, 16B per lane. LDS dest is the wave-uniform
// base; HW writes lane i at base + i*16B. Requires LINEAR (unpadded) LDS.
static __device__ __forceinline__ void gload16(const u16* g, u16* l) {
    __builtin_amdgcn_global_load_lds(
        (const __attribute__((address_space(1))) void*)g,
        (__attribute__((address_space(3))) void*)l, 16, 0, 0);
}

// ---------------------------------------------------------------------------
// One-shot convert: q,k,v fp32 -> bf16; W* fp32 [k][n] -> bf16 transposed [n][k].
// ---------------------------------------------------------------------------
__global__ __launch_bounds__(256)
void convert_kernel(const float* __restrict__ q, const float* __restrict__ k,
                    const float* __restrict__ v,
                    const float* __restrict__ Wq, const float* __restrict__ Wk,
                    const float* __restrict__ Wv, const float* __restrict__ Wo,
                    u16* __restrict__ qb, u16* __restrict__ kb, u16* __restrict__ vb,
                    u16* __restrict__ wqt, u16* __restrict__ wkt,
                    u16* __restrict__ wvt, u16* __restrict__ wot)
{
    __shared__ u16 T[64 * 80];
    const int tid = threadIdx.x;
    const int bid = blockIdx.x;
    if (bid < 3072) {
        int t = bid >> 10;
        const float* src = (t == 0) ? q : (t == 1) ? k : v;
        u16* dst = (t == 0) ? qb : (t == 1) ? kb : vb;
        size_t base = (size_t)(bid & 1023) * 4096;
#pragma unroll
        for (int i = 0; i < 4; ++i) {
            size_t e = base + (size_t)(tid + i * 256) * 4;
            float4 xv = *(const float4*)(src + e);
            ushort4 o;
            o.x = f2bf(xv.x); o.y = f2bf(xv.y); o.z = f2bf(xv.z); o.w = f2bf(xv.w);
            *(ushort4*)(dst + e) = o;
        }
    } else {
        int wbid = bid - 3072;
        int w = wbid >> 8;
        const float* src = (w == 0) ? Wq : (w == 1) ? Wk : (w == 2) ? Wv : Wo;
        u16* dst = (w == 0) ? wqt : (w == 1) ? wkt : (w == 2) ? wvt : wot;
        int t = wbid & 255;
        int k0 = (t >> 4) * 64, nt0 = (t & 15) * 64;
#pragma unroll
        for (int i = 0; i < 4; ++i) {
            int f = tid + i * 256;
            int kk = f >> 4, nn = (f & 15) * 4;
            float4 xv = *(const float4*)(src + (size_t)(k0 + kk) * Dd + nt0 + nn);
            T[(nn + 0) * 80 + kk] = f2bf(xv.x);
            T[(nn + 1) * 80 + kk] = f2bf(xv.y);
            T[(nn + 2) * 80 + kk] = f2bf(xv.z);
            T[(nn + 3) * 80 + kk] = f2bf(xv.w);
        }
        __syncthreads();
#pragma unroll
        for (int i = 0; i < 2; ++i) {
            int g = tid + i * 256;
            int nn = g >> 3, k8 = (g & 7) * 8;
            *(uint4*)(dst + (size_t)(nt0 + nn) * Dd + k0 + k8) =
                *(const uint4*)&T[nn * 80 + k8];
        }
    }
}

// ---------------------------------------------------------------------------
// bf16 MFMA GEMM — R11 version (swizzled staging+reads; conflicts fixed).
// R12 change: mode-1 (Q) scale folds log2(e) for exp2-domain softmax:
//   sc = 0.125 * 1.4426950408889634 = 0.18033688011112042
// R1 post-mortem still governs: do NOT grow acc/fragment count.
// ---------------------------------------------------------------------------
__global__ __launch_bounds__(256)
void gemm_bf16(const u16* __restrict__ X0, const u16* __restrict__ X1,
               const u16* __restrict__ X2,
               const u16* __restrict__ W0, const u16* __restrict__ W1,
               const u16* __restrict__ W2,
               const float* __restrict__ b0, const float* __restrict__ b1,
               const float* __restrict__ b2,
               u16* __restrict__ O0, u16* __restrict__ O1, u16* __restrict__ O2,
               float* __restrict__ OutF, int fused)
{
    __shared__ u16 As[128 * 64];
    __shared__ u16 Bs[64 * 64];

    const int tid = threadIdx.x;
    const int wv = tid >> 6, lane = tid & 63, l16 = lane & 15, quad = lane >> 4;
    const int n0 = blockIdx.x * 64, m0 = blockIdx.y * 128;
    const int z = blockIdx.z;

    const u16* X      = fused ? ((z == 0) ? X0 : (z == 1) ? X1 : X2) : X0;
    const u16* Wt     = fused ? ((z == 0) ? W0 : (z == 1) ? W1 : W2) : W0;
    const float* bias = fused ? ((z == 0) ? b0 : (z == 1) ? b1 : b2) : b0;
    u16* OutB         = (z == 0) ? O0 : (z == 1) ? O1 : O2;
    const int mode    = fused ? ((z == 0) ? 1 : (z == 1) ? 3 : 2) : 0;

    const int srow = tid >> 3;                       // p-chunk row 0..31
    const int scol = ((tid & 7) ^ (srow & 7)) * 8;   // swizzled global col (u16)
    const int sx   = (l16 & 7) * 8;                  // read-side XOR (u16)

    frag_cd acc[2][4];
#pragma unroll
    for (int ms = 0; ms < 2; ++ms)
#pragma unroll
        for (int n = 0; n < 4; ++n) acc[ms][n] = (frag_cd){0.f, 0.f, 0.f, 0.f};

    for (int k0 = 0; k0 < Dd; k0 += 64) {
        __syncthreads();   // prev-iter LDS readers done
#pragma unroll
        for (int p = 0; p < 4; ++p)
            gload16(&X[(size_t)(m0 + p * 32 + srow) * Dd + k0 + scol],
                    &As[p * 2048 + wv * 512]);
#pragma unroll
        for (int p = 0; p < 2; ++p)
            gload16(&Wt[(size_t)(n0 + p * 32 + srow) * Dd + k0 + scol],
                    &Bs[p * 2048 + wv * 512]);
        __syncthreads();   // compiler drains vmcnt(0) here: staging complete

#pragma unroll
        for (int ks = 0; ks < 2; ++ks) {
            frag_ab a0 = *(const frag_ab*)&As[(wv * 32 + l16) * 64 + ((ks * 32 + quad * 8) ^ sx)];
            frag_ab a1 = *(const frag_ab*)&As[(wv * 32 + 16 + l16) * 64 + ((ks * 32 + quad * 8) ^ sx)];
#pragma unroll
            for (int n = 0; n < 4; ++n) {
                frag_ab b = *(const frag_ab*)&Bs[(n * 16 + l16) * 64 + ((ks * 32 + quad * 8) ^ sx)];
                acc[0][n] = __builtin_amdgcn_mfma_f32_16x16x32_bf16(a0, b, acc[0][n], 0, 0, 0);
                acc[1][n] = __builtin_amdgcn_mfma_f32_16x16x32_bf16(a1, b, acc[1][n], 0, 0, 0);
            }
        }
    }

    float bv4[4];
#pragma unroll
    for (int n = 0; n < 4; ++n) bv4[n] = bias[n0 + n * 16 + l16];

    if (mode == 0) {
#pragma unroll
        for (int ms = 0; ms < 2; ++ms)
#pragma unroll
            for (int r = 0; r < 4; ++r) {
                int row = m0 + wv * 32 + ms * 16 + quad * 4 + r;
#pragma unroll
                for (int n = 0; n < 4; ++n)
                    OutF[(size_t)row * Dd + n0 + n * 16 + l16] = acc[ms][n][r] + bv4[n];
            }
    } else if (mode == 2) {
        const int h = n0 >> 6;
        const int b = m0 >> 11;
#pragma unroll
        for (int ms = 0; ms < 2; ++ms) {
            int sbase = (m0 & (Ss - 1)) + wv * 32 + ms * 16 + quad * 4;
#pragma unroll
            for (int n = 0; n < 4; ++n) {
                int d = n * 16 + l16;
                ushort4 o;
                o.x = f2bf(acc[ms][n][0] + bv4[n]);
                o.y = f2bf(acc[ms][n][1] + bv4[n]);
                o.z = f2bf(acc[ms][n][2] + bv4[n]);
                o.w = f2bf(acc[ms][n][3] + bv4[n]);
                *(ushort4*)&OutB[(((size_t)b * Hh + h) * DKk + d) * Ss + sbase] = o;
            }
        }
    } else {
        const int h = n0 >> 6;
        const float lg = 0.28782313662425575f;  // ln(10000)/32
        // mode 1 (Q): fold 1/sqrt(DK) AND log2(e) for exp2-domain softmax
        const float sc = (mode == 1) ? 0.18033688011112042f : 1.0f;
#pragma unroll
        for (int ms = 0; ms < 2; ++ms)
#pragma unroll
            for (int r = 0; r < 4; ++r) {
                int row = m0 + wv * 32 + ms * 16 + quad * 4 + r;
                int b = row >> 11, s = row & (Ss - 1);
                u16* orow = OutB + (((size_t)b * Hh + h) * Ss + s) * DKk;
#pragma unroll
                for (int n = 0; n < 2; ++n) {
                    int j = n * 16 + l16;
                    float ang = (float)s * __expf(-(float)j * lg);
                    float cv = cosf(ang), sv = sinf(ang);
                    float lo = acc[ms][n][r] + bv4[n];
                    float hi = acc[ms][n + 2][r] + bv4[n + 2];
                    orow[j]      = f2bf((lo * cv - hi * sv) * sc);
                    orow[j + 32] = f2bf((hi * cv + lo * sv) * sc);
                }
            }
    }
}

// ---------------------------------------------------------------------------
// Out-projection GEMM — R11 version (swizzled), unchanged.
// ---------------------------------------------------------------------------
__global__ __launch_bounds__(256)
void gemm_out(const u16* __restrict__ X0, const u16* __restrict__ W0,
              const float* __restrict__ b0, float* __restrict__ OutF)
{
    __shared__ u16 As[64 * 64];
    __shared__ u16 Bs[64 * 64];

    const int tid = threadIdx.x;
    const int wv = tid >> 6, lane = tid & 63, l16 = lane & 15, quad = lane >> 4;
    const int n0 = blockIdx.x * 64, m0 = blockIdx.y * 64;

    const int srow = tid >> 3;                       // p-chunk row 0..31
    const int scol = ((tid & 7) ^ (srow & 7)) * 8;   // swizzled global col (u16)
    const int sx   = (l16 & 7) * 8;                  // read-side XOR (u16)

    frag_cd acc[4];
#pragma unroll
    for (int n = 0; n < 4; ++n) acc[n] = (frag_cd){0.f, 0.f, 0.f, 0.f};

    for (int k0 = 0; k0 < Dd; k0 += 64) {
        __syncthreads();   // prev-iter LDS readers done
#pragma unroll
        for (int p = 0; p < 2; ++p) {
            gload16(&X0[(size_t)(m0 + p * 32 + srow) * Dd + k0 + scol],
                    &As[p * 2048 + wv * 512]);
            gload16(&W0[(size_t)(n0 + p * 32 + srow) * Dd + k0 + scol],
                    &Bs[p * 2048 + wv * 512]);
        }
        __syncthreads();   // drains vmcnt(0): staging complete

#pragma unroll
        for (int ks = 0; ks < 2; ++ks) {
            frag_ab a0 = *(const frag_ab*)&As[(wv * 16 + l16) * 64 + ((ks * 32 + quad * 8) ^ sx)];
#pragma unroll
            for (int n = 0; n < 4; ++n) {
                frag_ab b = *(const frag_ab*)&Bs[(n * 16 + l16) * 64 + ((ks * 32 + quad * 8) ^ sx)];
                acc[n] = __builtin_amdgcn_mfma_f32_16x16x32_bf16(a0, b, acc[n], 0, 0, 0);
            }
        }
    }

    float bv4[4];
#pragma unroll
    for (int n = 0; n < 4; ++n) bv4[n] = b0[n0 + n * 16 + l16];

#pragma unroll
    for (int r = 0; r < 4; ++r) {
        int row = m0 + wv * 16 + quad * 4 + r;
#pragma unroll
        for (int n = 0; n < 4; ++n)
            OutF[(size_t)row * Dd + n0 + n * 16 + l16] = acc[n][r] + bv4[n];
    }
}

// ---------------------------------------------------------------------------
// MFMA flash attention — R10 split-K frame + R12 VALU cuts:
//  * exp2 domain (Q pre-scaled by log2e in gemm): exp2f = bare v_exp_f32,
//    saves one v_mul per exp (16/iter/lane on the serial path).
//  * T13 defer-max, lane-local form: wave-uniform __any(mx > m_r + 8) gates
//    {a=exp2, l_r*=a, 4-shuffle broadcast, 16 of-muls}. Deferred iterations
//    (common case) run only max-tree + exp + sum. P <= 2^8 — bf16/f32 safe.
//    First iteration always rescales (m_r = -3e38). R6's failed attempt
//    bundled an LDS blunder on the row-distributed structure; lane-local
//    m_r makes this a single scalar compare (m214: +5% isolated).
// TRIPWIRES: absmax 0.0078125 (domain bug); attn >= 59.5us => VALU micro
// isn't the lever, structure at floor.
// ---------------------------------------------------------------------------
__global__ __launch_bounds__(256)
void attn_mfma(const u16* __restrict__ Q, const u16* __restrict__ K,
               const u16* __restrict__ Vt, u16* __restrict__ Aout,
               float* __restrict__ ofP, float* __restrict__ mlP)
{
    __shared__ u16 Ks[2][64 * 64];
    __shared__ u16 Vs[2][64 * 64];
    __shared__ u16 Ps[64 * 64];

    const int tid = threadIdx.x;
    const int wv = tid >> 6;
    const int lane = tid & 63;
    const int l16 = lane & 15;
    const int quad = lane >> 4;

    const int bh = blockIdx.y;
    // rotate chain assignment per bh to scatter long chains across dispatch
    const int x = (blockIdx.x + bh * 5) % 48;
    int q, kb0, kb1, half;
    if (x < 32) { q = x; kb0 = 0; kb1 = (x < 16) ? x : 15; half = 0; }
    else        { q = x - 16; kb0 = 16; kb1 = q; half = 1; }
    const int split = (q >= 16);
    const int q0 = q * 64;

    const size_t qkbase = (size_t)bh * Ss * DKk;
    const size_t vbase  = (size_t)bh * DKk * Ss;
    const int b = bh >> 4, h = bh & 15;

    const int srow = tid >> 3;                       // 0..31
    const int scol = ((tid & 7) ^ (srow & 7)) * 8;   // swizzled global col (u16)
    const int sx   = (l16 & 7) * 8;                  // read-side XOR (u16)

    // Q fragments straight to registers
    frag_ab qreg[2];
    {
        const u16* qrow = &Q[qkbase + (size_t)(q0 + wv * 16 + l16) * DKk];
#pragma unroll
        for (int h2 = 0; h2 < 2; ++h2)
            qreg[h2] = *(const frag_ab*)&qrow[h2 * 32 + quad * 8];
    }

    // prologue: KV tile kb0 -> buffer 0
    {
        const int k0p = kb0 * 64;
#pragma unroll
        for (int p = 0; p < 2; ++p) {
            gload16(&K[qkbase + (size_t)(k0p + p * 32 + srow) * DKk + scol],
                    &Ks[0][p * 2048 + wv * 512]);
            gload16(&Vt[vbase + (size_t)(p * 32 + srow) * Ss + k0p + scol],
                    &Vs[0][p * 2048 + wv * 512]);
        }
    }

    float m_r = -3.0e38f, l_r = 0.f;     // per-lane: q = wv*16 + l16 (log2 domain)
    frag_cd of[4];
#pragma unroll
    for (int n = 0; n < 4; ++n) of[n] = (frag_cd){0.f, 0.f, 0.f, 0.f};

    const int nkb = kb1 - kb0 + 1;
    for (int i = 0; i < nkb; ++i) {
        const int kb = kb0 + i;
        const int cur = i & 1;
        const u16* KsB = Ks[cur];
        const u16* VsB = Vs[cur];

        __syncthreads();   // drains vmcnt(0): buf[cur] staged; orders prev readers

        if (i < nkb - 1) {
            const int k0n = (kb + 1) * 64;
#pragma unroll
            for (int p = 0; p < 2; ++p) {
                gload16(&K[qkbase + (size_t)(k0n + p * 32 + srow) * DKk + scol],
                        &Ks[cur ^ 1][p * 2048 + wv * 512]);
                gload16(&Vt[vbase + (size_t)(p * 32 + srow) * Ss + k0n + scol],
                        &Vs[cur ^ 1][p * 2048 + wv * 512]);
            }
        }

        // QK^T, SWAPPED: sf[n][r] = S[q = wv*16+l16][k = n*16+quad*4+r]
        frag_cd sf[4];
#pragma unroll
        for (int n = 0; n < 4; ++n) sf[n] = (frag_cd){0.f, 0.f, 0.f, 0.f};
#pragma unroll
        for (int h2 = 0; h2 < 2; ++h2) {
#pragma unroll
            for (int n = 0; n < 4; ++n) {
                frag_ab kf = *(const frag_ab*)&KsB[(n * 16 + l16) * 64 + ((h2 * 32 + quad * 8) ^ sx)];
                sf[n] = __builtin_amdgcn_mfma_f32_16x16x32_bf16(kf, qreg[h2], sf[n], 0, 0, 0);
            }
        }

        if (kb == q) {
            const int qloc = wv * 16 + l16;
#pragma unroll
            for (int n = 0; n < 4; ++n)
#pragma unroll
                for (int r = 0; r < 4; ++r)
                    if (n * 16 + quad * 4 + r > qloc) sf[n][r] = -1.0e30f;
        }

        // --- lane-local row softmax, exp2 domain, defer-max ---
        frag_cd t0, t1;
#pragma unroll
        for (int r = 0; r < 4; ++r) {
            t0[r] = fmaxf(sf[0][r], sf[1][r]);
            t1[r] = fmaxf(sf[2][r], sf[3][r]);
        }
        float mx = fmaxf(fmaxf(fmaxf(t0[0], t1[0]), fmaxf(t0[1], t1[1])),
                         fmaxf(fmaxf(t0[2], t1[2]), fmaxf(t0[3], t1[3])));
        mx = fmaxf(mx, __shfl_xor(mx, 16));
        mx = fmaxf(mx, __shfl_xor(mx, 32));

        if (__any(mx > m_r + 8.0f)) {    // wave-uniform rescale path
            mx = fmaxf(mx, m_r);
            float a = exp2f(m_r - mx);
            m_r = mx;
            l_r *= a;
            float a4[4];
#pragma unroll
            for (int r = 0; r < 4; ++r)
                a4[r] = __shfl(a, (lane & 48) | (quad * 4 + r));
#pragma unroll
            for (int n = 0; n < 4; ++n)
#pragma unroll
                for (int r = 0; r < 4; ++r) of[n][r] *= a4[r];
        }
        // exp vs current m_r (deferred: values <= 2^8, bf16-safe)
        frag_cd s0, s1;
#pragma unroll
        for (int n = 0; n < 4; ++n)
#pragma unroll
            for (int r = 0; r < 4; ++r)
                sf[n][r] = exp2f(sf[n][r] - m_r);
#pragma unroll
        for (int r = 0; r < 4; ++r) {
            s0[r] = sf[0][r] + sf[1][r];
            s1[r] = sf[2][r] + sf[3][r];
        }
        float sum = ((s0[0] + s1[0]) + (s0[1] + s1[1])) +
                    ((s0[2] + s1[2]) + (s0[3] + s1[3]));
        sum += __shfl_xor(sum, 16);
        sum += __shfl_xor(sum, 32);
        l_r += sum;

        // P -> LDS: 4x ushort4 into the swizzled [64][64]
        {
            const int prow = wv * 16 + l16;
            const int px8  = (l16 & 7) << 3;
#pragma unroll
            for (int n = 0; n < 4; ++n) {
                ushort4 o;
                o.x = f2bf(sf[n][0]); o.y = f2bf(sf[n][1]);
                o.z = f2bf(sf[n][2]); o.w = f2bf(sf[n][3]);
                *(ushort4*)&Ps[prow * 64 + ((n * 16 + quad * 4) ^ px8)] = o;
            }
        }
        __threadfence_block();   // wave-private P strip: intra-wave order only

#pragma unroll
        for (int h2 = 0; h2 < 2; ++h2) {
            frag_ab pa = *(const frag_ab*)&Ps[(wv * 16 + l16) * 64 + ((h2 * 32 + quad * 8) ^ sx)];
#pragma unroll
            for (int n = 0; n < 4; ++n) {
                frag_ab vf = *(const frag_ab*)&VsB[(n * 16 + l16) * 64 + ((h2 * 32 + quad * 8) ^ sx)];
                of[n] = __builtin_amdgcn_mfma_f32_16x16x32_bf16(pa, vf, of[n], 0, 0, 0);
            }
        }
    }

    if (!split) {
        // direct output: 1/l at lane l16=q; broadcast to C-layout rows
        float linv = 1.f / l_r;
        float inv4[4];
#pragma unroll
        for (int r = 0; r < 4; ++r)
            inv4[r] = __shfl(linv, (lane & 48) | (quad * 4 + r));
#pragma unroll
        for (int r = 0; r < 4; ++r) {
            int row = q0 + wv * 16 + quad * 4 + r;
            u16* orow = Aout + ((size_t)b * Ss + row) * Dd + h * DKk;
#pragma unroll
            for (int n = 0; n < 4; ++n) orow[n * 16 + l16] = f2bf(of[n][r] * inv4[r]);
        }
    } else {
        // partials: of (unnormalized, f32) + m/l per q-row (m in log2 domain)
        const size_t pbase = (((size_t)bh * 16 + (q - 16)) * 2 + half) * 4096;
#pragma unroll
        for (int r = 0; r < 4; ++r) {
            int row = wv * 16 + quad * 4 + r;
#pragma unroll
            for (int n = 0; n < 4; ++n)
                ofP[pbase + (size_t)row * 64 + n * 16 + l16] = of[n][r];
        }
        if (quad == 0) {
            const size_t mb = (((size_t)bh * 16 + (q - 16)) * 2 + half) * 128;
            mlP[mb + wv * 16 + l16]      = m_r;
            mlP[mb + 64 + wv * 16 + l16] = l_r;
        }
    }
}

// ---------------------------------------------------------------------------
// Flash-decoding merge: combine the two partial halves of split q-tiles.
// R12: m/l partials are in LOG2 domain -> exp2f here.
// ---------------------------------------------------------------------------
__global__ __launch_bounds__(256)
void attn_merge(const float* __restrict__ ofP, const float* __restrict__ mlP,
                u16* __restrict__ Aout)
{
    const int s = blockIdx.x;    // 0..15 -> q-tile s+16
    const int bh = blockIdx.y;   // 0..31
    const int tid = threadIdx.x;
    const int row = tid >> 2;          // 0..63
    const int c0  = (tid & 3) * 16;    // 16 cols per thread
    const int b = bh >> 4, h = bh & 15;
    const int q0 = (s + 16) * 64;

    const size_t baseA = (((size_t)bh * 16 + s) * 2 + 0) * 4096 + (size_t)row * 64;
    const size_t baseB = baseA + 4096;
    const size_t mbA = (((size_t)bh * 16 + s) * 2 + 0) * 128;
    const size_t mbB = mbA + 128;

    float mA = mlP[mbA + row], lA = mlP[mbA + 64 + row];
    float mB = mlP[mbB + row], lB = mlP[mbB + 64 + row];
    float m  = fmaxf(mA, mB);
    float aA = exp2f(mA - m), aB = exp2f(mB - m);
    float inv = 1.f / (lA * aA + lB * aB);

    u16* orow = Aout + ((size_t)b * Ss + q0 + row) * Dd + h * DKk;
#pragma unroll
    for (int j4 = 0; j4 < 4; ++j4) {
        float4 vA = *(const float4*)&ofP[baseA + c0 + j4 * 4];
        float4 vB = *(const float4*)&ofP[baseB + c0 + j4 * 4];
        ushort4 o;
        o.x = f2bf((vA.x * aA + vB.x * aB) * inv);
        o.y = f2bf((vA.y * aA + vB.y * aB) * inv);
        o.z = f2bf((vA.z * aA + vB.z * aB) * inv);
        o.w = f2bf((vA.w * aA + vB.w * aB) * inv);
        *(ushort4*)&orow[c0 + j4 * 4] = o;
    }
}

extern "C" void kernel_launch(void* const* d_in, const int* in_sizes, int n_in,
                              void* d_out, int out_size, void* d_ws, size_t ws_size,
                              hipStream_t stream) {
    (void)in_sizes; (void)n_in; (void)out_size;
    const float* q  = (const float*)d_in[0];
    const float* k  = (const float*)d_in[1];
    const float* v  = (const float*)d_in[2];
    // d_in[3] = mask (tril causal) -- enforced analytically in attn_mfma
    const float* Wq = (const float*)d_in[4];
    const float* bq = (const float*)d_in[5];
    const float* Wk = (const float*)d_in[6];
    const float* bk = (const float*)d_in[7];
    const float* Wv = (const float*)d_in[8];
    const float* bv = (const float*)d_in[9];
    const float* Wo = (const float*)d_in[10];
    const float* bo = (const float*)d_in[11];
    float* out = (float*)d_out;

    const size_t E = (size_t)Bb * Ss * Dd;     // 4,194,304
    const size_t Wn = (size_t)Dd * Dd;         // 1,048,576
    const size_t need = (7 * E + 4 * Wn) * sizeof(u16);   // 64 MiB
    if (ws_size < need) return;
    u16* qa  = (u16*)d_ws;
    u16* ka  = qa + E;
    u16* va  = ka + E;
    u16* wqt = va + E;
    u16* wkt = wqt + Wn;
    u16* wvt = wkt + Wn;
    u16* wot = wvt + Wn;
    u16* Qh  = wot + Wn;
    u16* Kh  = Qh + E;
    u16* Vth = Kh + E;
    u16* Abf = Vth + E;

    // split-K partials overlay qa..ka (16 MiB) and va (512 KiB) — both dead
    // after the QKV gemm completes (stream-ordered).
    float* ofP = (float*)qa;
    float* mlP = (float*)va;

    convert_kernel<<<4096, 256, 0, stream>>>(q, k, v, Wq, Wk, Wv, Wo,
                                             qa, ka, va, wqt, wkt, wvt, wot);
    gemm_bf16<<<dim3(Dd / 64, BSn / 128, 3), 256, 0, stream>>>(
        qa, ka, va, wqt, wkt, wvt, bq, bk, bv, Qh, Kh, Vth, nullptr, 1);
    attn_mfma<<<dim3(48, Bb * Hh), 256, 0, stream>>>(Qh, Kh, Vth, Abf, ofP, mlP);
    attn_merge<<<dim3(16, Bb * Hh), 256, 0, stream>>>(ofP, mlP, Abf);
    gemm_out<<<dim3(Dd / 64, BSn / 64), 256, 0, stream>>>(Abf, wot, bo, out);
}

// Round 14
// 241.507 us; speedup vs baseline: 1.1593x; 1.0842x over previous
//
#include <hip/hip_runtime.h>
#include <hip/hip_bf16.h>
#include <math.h>

#define Bb 2
#define Ss 2048
#define Dd 1024
#define Hh 16
#define DKk 64
#define BSn (Bb*Ss)

typedef unsigned short u16;
typedef __attribute__((ext_vector_type(8))) short frag_ab;   // 8 bf16
typedef __attribute__((ext_vector_type(4))) float frag_cd;   // 4 f32

static __device__ __forceinline__ u16 f2bf(float x) {
    __hip_bfloat16 h = __float2bfloat16(x);
    return *reinterpret_cast<u16*>(&h);
}

// Direct global->LDS async copy, 16B per lane. LDS dest is the wave-uniform
// base; HW writes lane i at base + i*16B. Requires LINEAR (unpadded) LDS.
static __device__ __forceinline__ void gload16(const u16* g, u16* l) {
    __builtin_amdgcn_global_load_lds(
        (const __attribute__((address_space(1))) void*)g,
        (__attribute__((address_space(3))) void*)l, 16, 0, 0);
}

// ---------------------------------------------------------------------------
// One-shot convert: q,k,v fp32 -> bf16; W* fp32 [k][n] -> bf16 transposed [n][k].
// ---------------------------------------------------------------------------
__global__ __launch_bounds__(256)
void convert_kernel(const float* __restrict__ q, const float* __restrict__ k,
                    const float* __restrict__ v,
                    const float* __restrict__ Wq, const float* __restrict__ Wk,
                    const float* __restrict__ Wv, const float* __restrict__ Wo,
                    u16* __restrict__ qb, u16* __restrict__ kb, u16* __restrict__ vb,
                    u16* __restrict__ wqt, u16* __restrict__ wkt,
                    u16* __restrict__ wvt, u16* __restrict__ wot)
{
    __shared__ u16 T[64 * 80];
    const int tid = threadIdx.x;
    const int bid = blockIdx.x;
    if (bid < 3072) {
        int t = bid >> 10;
        const float* src = (t == 0) ? q : (t == 1) ? k : v;
        u16* dst = (t == 0) ? qb : (t == 1) ? kb : vb;
        size_t base = (size_t)(bid & 1023) * 4096;
#pragma unroll
        for (int i = 0; i < 4; ++i) {
            size_t e = base + (size_t)(tid + i * 256) * 4;
            float4 xv = *(const float4*)(src + e);
            ushort4 o;
            o.x = f2bf(xv.x); o.y = f2bf(xv.y); o.z = f2bf(xv.z); o.w = f2bf(xv.w);
            *(ushort4*)(dst + e) = o;
        }
    } else {
        int wbid = bid - 3072;
        int w = wbid >> 8;
        const float* src = (w == 0) ? Wq : (w == 1) ? Wk : (w == 2) ? Wv : Wo;
        u16* dst = (w == 0) ? wqt : (w == 1) ? wkt : (w == 2) ? wvt : wot;
        int t = wbid & 255;
        int k0 = (t >> 4) * 64, nt0 = (t & 15) * 64;
#pragma unroll
        for (int i = 0; i < 4; ++i) {
            int f = tid + i * 256;
            int kk = f >> 4, nn = (f & 15) * 4;
            float4 xv = *(const float4*)(src + (size_t)(k0 + kk) * Dd + nt0 + nn);
            T[(nn + 0) * 80 + kk] = f2bf(xv.x);
            T[(nn + 1) * 80 + kk] = f2bf(xv.y);
            T[(nn + 2) * 80 + kk] = f2bf(xv.z);
            T[(nn + 3) * 80 + kk] = f2bf(xv.w);
        }
        __syncthreads();
#pragma unroll
        for (int i = 0; i < 2; ++i) {
            int g = tid + i * 256;
            int nn = g >> 3, k8 = (g & 7) * 8;
            *(uint4*)(dst + (size_t)(nt0 + nn) * Dd + k0 + k8) =
                *(const uint4*)&T[nn * 80 + k8];
        }
    }
}

// ---------------------------------------------------------------------------
// QKV GEMM — R13 (resubmit; R13 bench was an infra failure, no data): 128x128
// tile, 8 waves (512 thr), each wave a 32x64 quadrant. PER-THREAD register
// footprint IDENTICAL to the proven R4 kernel: acc[2][4], a0/a1/b fragments,
// zero staging regs (gload_lds). This is the untried variant of R1 (which
// doubled per-thread acc and scratch-flooded).
// Mechanism: X HBM re-reads halve (8 n-blocks vs 16); staging issues/thread
// drop 6->4 per K-step; MFMA per barrier doubles. LDS 32KB, swizzled (R11).
// Grid (8,32,3)=768 = 3 blocks/CU, 24 waves/CU.
// TRIPWIRES: WRITE_SIZE ~24.6MB (R1 ghost: balloon => revert permanently);
// VGPR ~52; absmax 0.0078125; dur >= 58us => revert.
// ---------------------------------------------------------------------------
__global__ __launch_bounds__(512)
void gemm_qkv(const u16* __restrict__ X0, const u16* __restrict__ X1,
              const u16* __restrict__ X2,
              const u16* __restrict__ W0, const u16* __restrict__ W1,
              const u16* __restrict__ W2,
              const float* __restrict__ b0, const float* __restrict__ b1,
              const float* __restrict__ b2,
              u16* __restrict__ O0, u16* __restrict__ O1, u16* __restrict__ O2)
{
    __shared__ u16 As[128 * 64];
    __shared__ u16 Bs[128 * 64];

    const int tid = threadIdx.x;           // 0..511
    const int wv = tid >> 6;               // 0..7
    const int lane = tid & 63, l16 = lane & 15, quad = lane >> 4;
    const int wr = wv >> 1, wc = wv & 1;   // 4x2 wave grid (rows x cols)
    const int n0 = blockIdx.x * 128, m0 = blockIdx.y * 128;
    const int z = blockIdx.z;

    const u16* X      = (z == 0) ? X0 : (z == 1) ? X1 : X2;
    const u16* Wt     = (z == 0) ? W0 : (z == 1) ? W1 : W2;
    const float* bias = (z == 0) ? b0 : (z == 1) ? b1 : b2;
    u16* OutB         = (z == 0) ? O0 : (z == 1) ? O1 : O2;
    const int mode    = (z == 0) ? 1 : (z == 1) ? 3 : 2;

    const int srow = tid >> 3;                       // 0..63 (row within pass)
    const int scol = ((tid & 7) ^ (srow & 7)) * 8;   // swizzled global col (u16)
    const int sx   = (l16 & 7) * 8;                  // read-side XOR (u16)

    frag_cd acc[2][4];
#pragma unroll
    for (int ms = 0; ms < 2; ++ms)
#pragma unroll
        for (int n = 0; n < 4; ++n) acc[ms][n] = (frag_cd){0.f, 0.f, 0.f, 0.f};

    for (int k0 = 0; k0 < Dd; k0 += 64) {
        __syncthreads();   // prev-iter LDS readers done
#pragma unroll
        for (int p = 0; p < 2; ++p)
            gload16(&X[(size_t)(m0 + p * 64 + srow) * Dd + k0 + scol],
                    &As[p * 4096 + wv * 512]);
#pragma unroll
        for (int p = 0; p < 2; ++p)
            gload16(&Wt[(size_t)(n0 + p * 64 + srow) * Dd + k0 + scol],
                    &Bs[p * 4096 + wv * 512]);
        __syncthreads();   // drains vmcnt(0): staging complete

#pragma unroll
        for (int ks = 0; ks < 2; ++ks) {
            frag_ab a0 = *(const frag_ab*)&As[(wr * 32 + l16) * 64 + ((ks * 32 + quad * 8) ^ sx)];
            frag_ab a1 = *(const frag_ab*)&As[(wr * 32 + 16 + l16) * 64 + ((ks * 32 + quad * 8) ^ sx)];
#pragma unroll
            for (int n = 0; n < 4; ++n) {
                frag_ab b = *(const frag_ab*)&Bs[(wc * 64 + n * 16 + l16) * 64 + ((ks * 32 + quad * 8) ^ sx)];
                acc[0][n] = __builtin_amdgcn_mfma_f32_16x16x32_bf16(a0, b, acc[0][n], 0, 0, 0);
                acc[1][n] = __builtin_amdgcn_mfma_f32_16x16x32_bf16(a1, b, acc[1][n], 0, 0, 0);
            }
        }
    }

    float bv4[4];
#pragma unroll
    for (int n = 0; n < 4; ++n) bv4[n] = bias[n0 + wc * 64 + n * 16 + l16];

    const int h = (n0 + wc * 64) >> 6;   // each wave covers exactly one head

    if (mode == 2) {
        const int b = m0 >> 11;
#pragma unroll
        for (int ms = 0; ms < 2; ++ms) {
            int sbase = (m0 & (Ss - 1)) + wr * 32 + ms * 16 + quad * 4;
#pragma unroll
            for (int n = 0; n < 4; ++n) {
                int d = n * 16 + l16;
                ushort4 o;
                o.x = f2bf(acc[ms][n][0] + bv4[n]);
                o.y = f2bf(acc[ms][n][1] + bv4[n]);
                o.z = f2bf(acc[ms][n][2] + bv4[n]);
                o.w = f2bf(acc[ms][n][3] + bv4[n]);
                *(ushort4*)&OutB[(((size_t)b * Hh + h) * DKk + d) * Ss + sbase] = o;
            }
        }
    } else {
        const float lg = 0.28782313662425575f;  // ln(10000)/32
        const float sc = (mode == 1) ? 0.125f : 1.0f;
#pragma unroll
        for (int ms = 0; ms < 2; ++ms)
#pragma unroll
            for (int r = 0; r < 4; ++r) {
                int row = m0 + wr * 32 + ms * 16 + quad * 4 + r;
                int b = row >> 11, s = row & (Ss - 1);
                u16* orow = OutB + (((size_t)b * Hh + h) * Ss + s) * DKk;
#pragma unroll
                for (int n = 0; n < 2; ++n) {
                    int j = n * 16 + l16;
                    float ang = (float)s * __expf(-(float)j * lg);
                    float cv = cosf(ang), sv = sinf(ang);
                    float lo = acc[ms][n][r] + bv4[n];
                    float hi = acc[ms][n + 2][r] + bv4[n + 2];
                    orow[j]      = f2bf((lo * cv - hi * sv) * sc);
                    orow[j + 32] = f2bf((hi * cv + lo * sv) * sc);
                }
            }
    }
}

// ---------------------------------------------------------------------------
// Out-projection GEMM — R11 version (swizzled), unchanged.
// ---------------------------------------------------------------------------
__global__ __launch_bounds__(256)
void gemm_out(const u16* __restrict__ X0, const u16* __restrict__ W0,
              const float* __restrict__ b0, float* __restrict__ OutF)
{
    __shared__ u16 As[64 * 64];
    __shared__ u16 Bs[64 * 64];

    const int tid = threadIdx.x;
    const int wv = tid >> 6, lane = tid & 63, l16 = lane & 15, quad = lane >> 4;
    const int n0 = blockIdx.x * 64, m0 = blockIdx.y * 64;

    const int srow = tid >> 3;                       // p-chunk row 0..31
    const int scol = ((tid & 7) ^ (srow & 7)) * 8;   // swizzled global col (u16)
    const int sx   = (l16 & 7) * 8;                  // read-side XOR (u16)

    frag_cd acc[4];
#pragma unroll
    for (int n = 0; n < 4; ++n) acc[n] = (frag_cd){0.f, 0.f, 0.f, 0.f};

    for (int k0 = 0; k0 < Dd; k0 += 64) {
        __syncthreads();   // prev-iter LDS readers done
#pragma unroll
        for (int p = 0; p < 2; ++p) {
            gload16(&X0[(size_t)(m0 + p * 32 + srow) * Dd + k0 + scol],
                    &As[p * 2048 + wv * 512]);
            gload16(&W0[(size_t)(n0 + p * 32 + srow) * Dd + k0 + scol],
                    &Bs[p * 2048 + wv * 512]);
        }
        __syncthreads();   // drains vmcnt(0): staging complete

#pragma unroll
        for (int ks = 0; ks < 2; ++ks) {
            frag_ab a0 = *(const frag_ab*)&As[(wv * 16 + l16) * 64 + ((ks * 32 + quad * 8) ^ sx)];
#pragma unroll
            for (int n = 0; n < 4; ++n) {
                frag_ab b = *(const frag_ab*)&Bs[(n * 16 + l16) * 64 + ((ks * 32 + quad * 8) ^ sx)];
                acc[n] = __builtin_amdgcn_mfma_f32_16x16x32_bf16(a0, b, acc[n], 0, 0, 0);
            }
        }
    }

    float bv4[4];
#pragma unroll
    for (int n = 0; n < 4; ++n) bv4[n] = b0[n0 + n * 16 + l16];

#pragma unroll
    for (int r = 0; r < 4; ++r) {
        int row = m0 + wv * 16 + quad * 4 + r;
#pragma unroll
        for (int n = 0; n < 4; ++n)
            OutF[(size_t)row * Dd + n0 + n * 16 + l16] = acc[n][r] + bv4[n];
    }
}

// ---------------------------------------------------------------------------
// MFMA flash attention — R11 split-K version VERBATIM (measured 60.9us).
// R12's defer-max/exp2 REVERTED: regressed 60.9->65.4 (VALUBusy 42.6->47.9;
// in-loop branch hurt scheduling more than saved multiplies — same verdict
// as R6 in its other form; avenue closed).
// ---------------------------------------------------------------------------
__global__ __launch_bounds__(256)
void attn_mfma(const u16* __restrict__ Q, const u16* __restrict__ K,
               const u16* __restrict__ Vt, u16* __restrict__ Aout,
               float* __restrict__ ofP, float* __restrict__ mlP)
{
    __shared__ u16 Ks[2][64 * 64];
    __shared__ u16 Vs[2][64 * 64];
    __shared__ u16 Ps[64 * 64];

    const int tid = threadIdx.x;
    const int wv = tid >> 6;
    const int lane = tid & 63;
    const int l16 = lane & 15;
    const int quad = lane >> 4;

    const int bh = blockIdx.y;
    // rotate chain assignment per bh to scatter long chains across dispatch
    const int x = (blockIdx.x + bh * 5) % 48;
    int q, kb0, kb1, half;
    if (x < 32) { q = x; kb0 = 0; kb1 = (x < 16) ? x : 15; half = 0; }
    else        { q = x - 16; kb0 = 16; kb1 = q; half = 1; }
    const int split = (q >= 16);
    const int q0 = q * 64;

    const size_t qkbase = (size_t)bh * Ss * DKk;
    const size_t vbase  = (size_t)bh * DKk * Ss;
    const int b = bh >> 4, h = bh & 15;

    const int srow = tid >> 3;                       // 0..31
    const int scol = ((tid & 7) ^ (srow & 7)) * 8;   // swizzled global col (u16)
    const int sx   = (l16 & 7) * 8;                  // read-side XOR (u16)

    // Q fragments straight to registers
    frag_ab qreg[2];
    {
        const u16* qrow = &Q[qkbase + (size_t)(q0 + wv * 16 + l16) * DKk];
#pragma unroll
        for (int h2 = 0; h2 < 2; ++h2)
            qreg[h2] = *(const frag_ab*)&qrow[h2 * 32 + quad * 8];
    }

    // prologue: KV tile kb0 -> buffer 0
    {
        const int k0p = kb0 * 64;
#pragma unroll
        for (int p = 0; p < 2; ++p) {
            gload16(&K[qkbase + (size_t)(k0p + p * 32 + srow) * DKk + scol],
                    &Ks[0][p * 2048 + wv * 512]);
            gload16(&Vt[vbase + (size_t)(p * 32 + srow) * Ss + k0p + scol],
                    &Vs[0][p * 2048 + wv * 512]);
        }
    }

    float m_r = -3.0e38f, l_r = 0.f;     // per-lane: q = wv*16 + l16
    frag_cd of[4];
#pragma unroll
    for (int n = 0; n < 4; ++n) of[n] = (frag_cd){0.f, 0.f, 0.f, 0.f};

    const int nkb = kb1 - kb0 + 1;
    for (int i = 0; i < nkb; ++i) {
        const int kb = kb0 + i;
        const int cur = i & 1;
        const u16* KsB = Ks[cur];
        const u16* VsB = Vs[cur];

        __syncthreads();   // drains vmcnt(0): buf[cur] staged; orders prev readers

        if (i < nkb - 1) {
            const int k0n = (kb + 1) * 64;
#pragma unroll
            for (int p = 0; p < 2; ++p) {
                gload16(&K[qkbase + (size_t)(k0n + p * 32 + srow) * DKk + scol],
                        &Ks[cur ^ 1][p * 2048 + wv * 512]);
                gload16(&Vt[vbase + (size_t)(p * 32 + srow) * Ss + k0n + scol],
                        &Vs[cur ^ 1][p * 2048 + wv * 512]);
            }
        }

        // QK^T, SWAPPED: sf[n][r] = S[q = wv*16+l16][k = n*16+quad*4+r]
        frag_cd sf[4];
#pragma unroll
        for (int n = 0; n < 4; ++n) sf[n] = (frag_cd){0.f, 0.f, 0.f, 0.f};
#pragma unroll
        for (int h2 = 0; h2 < 2; ++h2) {
#pragma unroll
            for (int n = 0; n < 4; ++n) {
                frag_ab kf = *(const frag_ab*)&KsB[(n * 16 + l16) * 64 + ((h2 * 32 + quad * 8) ^ sx)];
                sf[n] = __builtin_amdgcn_mfma_f32_16x16x32_bf16(kf, qreg[h2], sf[n], 0, 0, 0);
            }
        }

        if (kb == q) {
            const int qloc = wv * 16 + l16;
#pragma unroll
            for (int n = 0; n < 4; ++n)
#pragma unroll
                for (int r = 0; r < 4; ++r)
                    if (n * 16 + quad * 4 + r > qloc) sf[n][r] = -1.0e30f;
        }

        // --- lane-local row softmax (R9) ---
        frag_cd t0, t1;
#pragma unroll
        for (int r = 0; r < 4; ++r) {
            t0[r] = fmaxf(sf[0][r], sf[1][r]);
            t1[r] = fmaxf(sf[2][r], sf[3][r]);
        }
        float mx = fmaxf(fmaxf(fmaxf(t0[0], t1[0]), fmaxf(t0[1], t1[1])),
                         fmaxf(fmaxf(t0[2], t1[2]), fmaxf(t0[3], t1[3])));
        mx = fmaxf(mx, m_r);
        mx = fmaxf(mx, __shfl_xor(mx, 16));
        mx = fmaxf(mx, __shfl_xor(mx, 32));

        float a = __expf(m_r - mx);
        m_r = mx;

        frag_cd s0, s1;
#pragma unroll
        for (int n = 0; n < 4; ++n)
#pragma unroll
            for (int r = 0; r < 4; ++r)
                sf[n][r] = __expf(sf[n][r] - mx);
#pragma unroll
        for (int r = 0; r < 4; ++r) {
            s0[r] = sf[0][r] + sf[1][r];
            s1[r] = sf[2][r] + sf[3][r];
        }
        float sum = ((s0[0] + s1[0]) + (s0[1] + s1[1])) +
                    ((s0[2] + s1[2]) + (s0[3] + s1[3]));
        sum += __shfl_xor(sum, 16);
        sum += __shfl_xor(sum, 32);
        l_r = l_r * a + sum;

        float a4[4];
#pragma unroll
        for (int r = 0; r < 4; ++r)
            a4[r] = __shfl(a, (lane & 48) | (quad * 4 + r));
#pragma unroll
        for (int n = 0; n < 4; ++n)
#pragma unroll
            for (int r = 0; r < 4; ++r) of[n][r] *= a4[r];

        // P -> LDS: 4x ushort4 into the swizzled [64][64]
        {
            const int prow = wv * 16 + l16;
            const int px8  = (l16 & 7) << 3;
#pragma unroll
            for (int n = 0; n < 4; ++n) {
                ushort4 o;
                o.x = f2bf(sf[n][0]); o.y = f2bf(sf[n][1]);
                o.z = f2bf(sf[n][2]); o.w = f2bf(sf[n][3]);
                *(ushort4*)&Ps[prow * 64 + ((n * 16 + quad * 4) ^ px8)] = o;
            }
        }
        __threadfence_block();   // wave-private P strip: intra-wave order only

#pragma unroll
        for (int h2 = 0; h2 < 2; ++h2) {
            frag_ab pa = *(const frag_ab*)&Ps[(wv * 16 + l16) * 64 + ((h2 * 32 + quad * 8) ^ sx)];
#pragma unroll
            for (int n = 0; n < 4; ++n) {
                frag_ab vf = *(const frag_ab*)&VsB[(n * 16 + l16) * 64 + ((h2 * 32 + quad * 8) ^ sx)];
                of[n] = __builtin_amdgcn_mfma_f32_16x16x32_bf16(pa, vf, of[n], 0, 0, 0);
            }
        }
    }

    if (!split) {
        // direct output: 1/l at lane l16=q; broadcast to C-layout rows
        float linv = 1.f / l_r;
        float inv4[4];
#pragma unroll
        for (int r = 0; r < 4; ++r)
            inv4[r] = __shfl(linv, (lane & 48) | (quad * 4 + r));
#pragma unroll
        for (int r = 0; r < 4; ++r) {
            int row = q0 + wv * 16 + quad * 4 + r;
            u16* orow = Aout + ((size_t)b * Ss + row) * Dd + h * DKk;
#pragma unroll
            for (int n = 0; n < 4; ++n) orow[n * 16 + l16] = f2bf(of[n][r] * inv4[r]);
        }
    } else {
        // partials: of (unnormalized, f32) + m/l per q-row
        const size_t pbase = (((size_t)bh * 16 + (q - 16)) * 2 + half) * 4096;
#pragma unroll
        for (int r = 0; r < 4; ++r) {
            int row = wv * 16 + quad * 4 + r;
#pragma unroll
            for (int n = 0; n < 4; ++n)
                ofP[pbase + (size_t)row * 64 + n * 16 + l16] = of[n][r];
        }
        if (quad == 0) {
            const size_t mb = (((size_t)bh * 16 + (q - 16)) * 2 + half) * 128;
            mlP[mb + wv * 16 + l16]      = m_r;
            mlP[mb + 64 + wv * 16 + l16] = l_r;
        }
    }
}

// ---------------------------------------------------------------------------
// Flash-decoding merge: combine the two partial halves of split q-tiles.
// ---------------------------------------------------------------------------
__global__ __launch_bounds__(256)
void attn_merge(const float* __restrict__ ofP, const float* __restrict__ mlP,
                u16* __restrict__ Aout)
{
    const int s = blockIdx.x;    // 0..15 -> q-tile s+16
    const int bh = blockIdx.y;   // 0..31
    const int tid = threadIdx.x;
    const int row = tid >> 2;          // 0..63
    const int c0  = (tid & 3) * 16;    // 16 cols per thread
    const int b = bh >> 4, h = bh & 15;
    const int q0 = (s + 16) * 64;

    const size_t baseA = (((size_t)bh * 16 + s) * 2 + 0) * 4096 + (size_t)row * 64;
    const size_t baseB = baseA + 4096;
    const size_t mbA = (((size_t)bh * 16 + s) * 2 + 0) * 128;
    const size_t mbB = mbA + 128;

    float mA = mlP[mbA + row], lA = mlP[mbA + 64 + row];
    float mB = mlP[mbB + row], lB = mlP[mbB + 64 + row];
    float m  = fmaxf(mA, mB);
    float aA = __expf(mA - m), aB = __expf(mB - m);
    float inv = 1.f / (lA * aA + lB * aB);

    u16* orow = Aout + ((size_t)b * Ss + q0 + row) * Dd + h * DKk;
#pragma unroll
    for (int j4 = 0; j4 < 4; ++j4) {
        float4 vA = *(const float4*)&ofP[baseA + c0 + j4 * 4];
        float4 vB = *(const float4*)&ofP[baseB + c0 + j4 * 4];
        ushort4 o;
        o.x = f2bf((vA.x * aA + vB.x * aB) * inv);
        o.y = f2bf((vA.y * aA + vB.y * aB) * inv);
        o.z = f2bf((vA.z * aA + vB.z * aB) * inv);
        o.w = f2bf((vA.w * aA + vB.w * aB) * inv);
        *(ushort4*)&orow[c0 + j4 * 4] = o;
    }
}

extern "C" void kernel_launch(void* const* d_in, const int* in_sizes, int n_in,
                              void* d_out, int out_size, void* d_ws, size_t ws_size,
                              hipStream_t stream) {
    (void)in_sizes; (void)n_in; (void)out_size;
    const float* q  = (const float*)d_in[0];
    const float* k  = (const float*)d_in[1];
    const float* v  = (const float*)d_in[2];
    // d_in[3] = mask (tril causal) -- enforced analytically in attn_mfma
    const float* Wq = (const float*)d_in[4];
    const float* bq = (const float*)d_in[5];
    const float* Wk = (const float*)d_in[6];
    const float* bk = (const float*)d_in[7];
    const float* Wv = (const float*)d_in[8];
    const float* bv = (const float*)d_in[9];
    const float* Wo = (const float*)d_in[10];
    const float* bo = (const float*)d_in[11];
    float* out = (float*)d_out;

    const size_t E = (size_t)Bb * Ss * Dd;     // 4,194,304
    const size_t Wn = (size_t)Dd * Dd;         // 1,048,576
    const size_t need = (7 * E + 4 * Wn) * sizeof(u16);   // 64 MiB
    if (ws_size < need) return;
    u16* qa  = (u16*)d_ws;
    u16* ka  = qa + E;
    u16* va  = ka + E;
    u16* wqt = va + E;
    u16* wkt = wqt + Wn;
    u16* wvt = wkt + Wn;
    u16* wot = wvt + Wn;
    u16* Qh  = wot + Wn;
    u16* Kh  = Qh + E;
    u16* Vth = Kh + E;
    u16* Abf = Vth + E;

    // split-K partials overlay qa..ka (16 MiB) and va (512 KiB) — both dead
    // after the QKV gemm completes (stream-ordered).
    float* ofP = (float*)qa;
    float* mlP = (float*)va;

    convert_kernel<<<4096, 256, 0, stream>>>(q, k, v, Wq, Wk, Wv, Wo,
                                             qa, ka, va, wqt, wkt, wvt, wot);
    gemm_qkv<<<dim3(Dd / 128, BSn / 128, 3), 512, 0, stream>>>(
        qa, ka, va, wqt, wkt, wvt, bq, bk, bv, Qh, Kh, Vth);
    attn_mfma<<<dim3(48, Bb * Hh), 256, 0, stream>>>(Qh, Kh, Vth, Abf, ofP, mlP);
    attn_merge<<<dim3(16, Bb * Hh), 256, 0, stream>>>(ofP, mlP, Abf);
    gemm_out<<<dim3(Dd / 64, BSn / 64), 256, 0, stream>>>(Abf, wot, bo, out);
}